// Round 6
// baseline (314.399 us; speedup 1.0000x reference)
//
#include <hip/hip_runtime.h>

#define DD 128
#define HH 8

typedef float f32x4 __attribute__((ext_vector_type(4)));
typedef short s16x8 __attribute__((ext_vector_type(8)));

__device__ __forceinline__ ushort f2b(float f) {
  unsigned u = __float_as_uint(f);
  unsigned r = u + 0x7fffu + ((u >> 16) & 1u);
  return (ushort)(r >> 16);
}
__device__ __forceinline__ float b2f(ushort b) {
  return __uint_as_float(((unsigned)b) << 16);
}
__device__ __forceinline__ void atomAddF(float* p, float v) {
#if defined(__HIP_DEVICE_COMPILE__)
  unsafeAtomicAdd(p, v);
#else
  atomicAdd(p, v);
#endif
}
__device__ __forceinline__ float lrelu(float v) { return fmaxf(v, 0.2f * v); }

// pack W[k][n] (128x128 row-major) into B-fragment order for 16x16x32 MFMA:
// P[((q*8+c)*64 + l)*8 + j] = W[q*32 + (l>>4)*8 + j][c*16 + (l&15)]
__device__ __forceinline__ void packW_idx(int i, int& k, int& n) {
  int j = i & 7, l = (i >> 3) & 63, tile = i >> 9;
  int q = tile >> 3, c = tile & 7;
  k = q * 32 + ((l >> 4) << 3) + j;
  n = c * 16 + (l & 15);
}

// ---------- fused prep: x->bf16 conv, Wl/Wr pack, degree histogram ----------
__global__ __launch_bounds__(256) void k_prep(const float* __restrict__ x,
    ushort* __restrict__ xb, int total4, const float* __restrict__ Wl,
    const float* __restrict__ Wr, ushort* __restrict__ WlP,
    ushort* __restrict__ WrP, const int* __restrict__ ei,
    int* __restrict__ deg, int E, int convB, int packB) {
  int b = blockIdx.x;
  if (b < convB) {
    int i = b * 256 + threadIdx.x;
    if (i < total4) {
      float4 v = ((const float4*)x)[i];
      ushort4 o;
      o.x = f2b(v.x); o.y = f2b(v.y); o.z = f2b(v.z); o.w = f2b(v.w);
      ((ushort4*)xb)[i] = o;
    }
  } else if (b < convB + packB) {
    int t = (b - convB) * 256 + threadIdx.x;  // 0..32767
    int side = t >> 14;
    int i = t & 16383;
    int k, n;
    packW_idx(i, k, n);
    if (side) WrP[i] = f2b(Wr[k * DD + n]);
    else      WlP[i] = f2b(Wl[k * DD + n]);
  } else {
    int e = (b - convB - packB) * 256 + threadIdx.x;
    if (e < E) atomicAdd(&deg[ei[E + e]], 1);
  }
}

// ---------- CSR scan ----------
__global__ __launch_bounds__(256) void k_part(const int* __restrict__ deg,
    int* __restrict__ rowstart, int* __restrict__ bsum, int N) {
  __shared__ int sc[256];
  int t = threadIdx.x;
  int i = blockIdx.x * 256 + t;
  int v = (i < N) ? deg[i] : 0;
  sc[t] = v;
  __syncthreads();
  for (int off = 1; off < 256; off <<= 1) {
    int u = (t >= off) ? sc[t - off] : 0;
    __syncthreads();
    sc[t] += u;
    __syncthreads();
  }
  if (i < N) rowstart[i] = sc[t] - v;
  if (t == 255) bsum[blockIdx.x] = sc[255];
}

__global__ __launch_bounds__(1024) void k_mid(const int* __restrict__ bsum,
    int* __restrict__ boff, int* __restrict__ rowstartN, int B) {
  __shared__ int sc[1024];
  int t = threadIdx.x;
  int v = (t < B) ? bsum[t] : 0;
  sc[t] = v;
  __syncthreads();
  for (int off = 1; off < 1024; off <<= 1) {
    int u = (t >= off) ? sc[t - off] : 0;
    __syncthreads();
    sc[t] += u;
    __syncthreads();
  }
  if (t < B) boff[t] = sc[t] - v;
  if (t == 1023) *rowstartN = sc[1023];
}

__global__ __launch_bounds__(256) void k_apply(int* __restrict__ rowstart,
    int* __restrict__ cursor, const int* __restrict__ boff, int N) {
  int i = blockIdx.x * 256 + threadIdx.x;
  if (i < N) {
    int r = rowstart[i] + boff[blockIdx.x];
    rowstart[i] = r;
    cursor[i] = r;
  }
}

__global__ __launch_bounds__(256) void k_fill(const int* __restrict__ ei,
    int* __restrict__ cursor, int* __restrict__ csr_src, int E) {
  int e = blockIdx.x * 256 + threadIdx.x;
  if (e < E) {
    int d = ei[E + e];
    int pos = atomicAdd(&cursor[d], 1);
    csr_src[pos] = ei[e];
  }
}

// ---------- MFMA GEMM: out_l/out_r (bf16) = A @ Wl/Wr + bias ----------
__global__ __launch_bounds__(256) void k_mm_lr(const ushort* __restrict__ xb,
    const ushort* __restrict__ WlP, const ushort* __restrict__ WrP,
    const float* __restrict__ bl, const float* __restrict__ br,
    ushort* __restrict__ xlb, ushort* __restrict__ xrb, int N) {
  __shared__ ushort sW[2][16384];
  {
    const uint4* a = (const uint4*)WlP;
    const uint4* b = (const uint4*)WrP;
    uint4* da = (uint4*)sW[0];
    uint4* db = (uint4*)sW[1];
    for (int i = threadIdx.x; i < 2048; i += 256) { da[i] = a[i]; db[i] = b[i]; }
  }
  __syncthreads();
  int lane = threadIdx.x & 63;
  int wv = threadIdx.x >> 6;
  int rbase = blockIdx.x * 64 + wv * 16;
  int arow = rbase + (lane & 15);
  if (arow >= N) arow = 0;  // stores masked below
  const ushort* ap = xb + (size_t)arow * DD + ((lane >> 4) << 3);
  s16x8 afr[4];
#pragma unroll
  for (int q = 0; q < 4; q++) afr[q] = *(const s16x8*)(ap + q * 32);
  f32x4 accL[8] = {}, accR[8] = {};
#pragma unroll
  for (int q = 0; q < 4; q++) {
#pragma unroll
    for (int c = 0; c < 8; c++) {
      s16x8 bL = *(const s16x8*)(sW[0] + ((q * 8 + c) * 64 + lane) * 8);
      accL[c] = __builtin_amdgcn_mfma_f32_16x16x32_bf16(afr[q], bL, accL[c], 0, 0, 0);
      s16x8 bR = *(const s16x8*)(sW[1] + ((q * 8 + c) * 64 + lane) * 8);
      accR[c] = __builtin_amdgcn_mfma_f32_16x16x32_bf16(afr[q], bR, accR[c], 0, 0, 0);
    }
  }
  int r0 = rbase + ((lane >> 4) << 2);
  int colb = lane & 15;
#pragma unroll
  for (int c = 0; c < 8; c++) {
    int col = c * 16 + colb;
    float vbl = bl[col], vbr = br[col];
#pragma unroll
    for (int r = 0; r < 4; r++) {
      int row = r0 + r;
      if (row < N) {
        xlb[(size_t)row * DD + col] = f2b(accL[c][r] + vbl);
        xrb[(size_t)row * DD + col] = f2b(accR[c][r] + vbr);
      }
    }
  }
}

// ---------- MFMA GEMM: z (f32 + bf16 copy) and v2 (f32) from hfeat ----------
__global__ __launch_bounds__(256) void k_mm_z(const ushort* __restrict__ hfb,
    const ushort* __restrict__ W1P, const ushort* __restrict__ W2P,
    const float* __restrict__ b1p, const float* __restrict__ b2pp,
    float* __restrict__ z, ushort* __restrict__ zb, float* __restrict__ v2,
    int N) {
  __shared__ ushort sW[2][16384];
  {
    const uint4* a = (const uint4*)W1P;
    const uint4* b = (const uint4*)W2P;
    uint4* da = (uint4*)sW[0];
    uint4* db = (uint4*)sW[1];
    for (int i = threadIdx.x; i < 2048; i += 256) { da[i] = a[i]; db[i] = b[i]; }
  }
  __syncthreads();
  int lane = threadIdx.x & 63;
  int wv = threadIdx.x >> 6;
  int rbase = blockIdx.x * 64 + wv * 16;
  int arow = rbase + (lane & 15);
  if (arow >= N) arow = 0;
  const ushort* ap = hfb + (size_t)arow * DD + ((lane >> 4) << 3);
  s16x8 afr[4];
#pragma unroll
  for (int q = 0; q < 4; q++) afr[q] = *(const s16x8*)(ap + q * 32);
  f32x4 acc1[8] = {}, acc2[8] = {};
#pragma unroll
  for (int q = 0; q < 4; q++) {
#pragma unroll
    for (int c = 0; c < 8; c++) {
      s16x8 b1 = *(const s16x8*)(sW[0] + ((q * 8 + c) * 64 + lane) * 8);
      acc1[c] = __builtin_amdgcn_mfma_f32_16x16x32_bf16(afr[q], b1, acc1[c], 0, 0, 0);
      s16x8 b2 = *(const s16x8*)(sW[1] + ((q * 8 + c) * 64 + lane) * 8);
      acc2[c] = __builtin_amdgcn_mfma_f32_16x16x32_bf16(afr[q], b2, acc2[c], 0, 0, 0);
    }
  }
  int r0 = rbase + ((lane >> 4) << 2);
  int colb = lane & 15;
#pragma unroll
  for (int c = 0; c < 8; c++) {
    int col = c * 16 + colb;
    float vb1 = b1p[col], vb2 = b2pp[col];
#pragma unroll
    for (int r = 0; r < 4; r++) {
      int row = r0 + r;
      if (row < N) {
        float zv = acc1[c][r] + vb1;
        z[(size_t)row * DD + col] = zv;
        zb[(size_t)row * DD + col] = f2b(zv);
        v2[(size_t)row * DD + col] = acc2[c][r] + vb2;
      }
    }
  }
}

// ---------- GAT aggregation: wave/node, fixed-ref softmax (self logit) ----
// softmax shift-invariance: exp(t - m0)/sum is exact; logits are O(1) here,
// clamp at 60 guards fp32 range.
__global__ __launch_bounds__(256) void k_agg(const ushort* __restrict__ xlb,
    const ushort* __restrict__ xrb, const int* __restrict__ rowstart,
    const int* __restrict__ csr_src, const float* __restrict__ att,
    const float* __restrict__ cb, ushort* __restrict__ hfb, int N) {
  int lane = threadIdx.x & 63;
  int d = (blockIdx.x * 256 + threadIdx.x) >> 6;
  if (d >= N) return;
  float2 a = ((const float2*)att)[lane];
  ushort2 rv = ((const ushort2*)(xrb + (size_t)d * DD))[lane];
  float2 r = {b2f(rv.x), b2f(rv.y)};
  // self loop seeds reference m0; e_self = exp(0) = 1
  ushort2 gv = ((const ushort2*)(xlb + (size_t)d * DD))[lane];
  float2 g0 = {b2f(gv.x), b2f(gv.y)};
  float t0 = lrelu(g0.x + r.x) * a.x + lrelu(g0.y + r.y) * a.y;
#pragma unroll
  for (int o = 4; o; o >>= 1) t0 += __shfl_xor(t0, o);
  float m0 = t0;
  float den0 = 1.f, den1 = 0.f, den2 = 0.f, den3 = 0.f;
  float2 acc0 = g0, acc1 = {0.f, 0.f}, acc2 = {0.f, 0.f}, acc3 = {0.f, 0.f};
  int i0 = rowstart[d], i1 = rowstart[d + 1];
  int i = i0;
  for (; i + 4 <= i1; i += 4) {
    int s0 = csr_src[i], s1 = csr_src[i + 1];
    int s2 = csr_src[i + 2], s3 = csr_src[i + 3];
    ushort2 va = ((const ushort2*)(xlb + (size_t)s0 * DD))[lane];
    ushort2 vb = ((const ushort2*)(xlb + (size_t)s1 * DD))[lane];
    ushort2 vc = ((const ushort2*)(xlb + (size_t)s2 * DD))[lane];
    ushort2 vd = ((const ushort2*)(xlb + (size_t)s3 * DD))[lane];
    float2 ga = {b2f(va.x), b2f(va.y)};
    float2 gb = {b2f(vb.x), b2f(vb.y)};
    float2 gc = {b2f(vc.x), b2f(vc.y)};
    float2 gd = {b2f(vd.x), b2f(vd.y)};
    float ta = lrelu(ga.x + r.x) * a.x + lrelu(ga.y + r.y) * a.y;
    float tb = lrelu(gb.x + r.x) * a.x + lrelu(gb.y + r.y) * a.y;
    float tc = lrelu(gc.x + r.x) * a.x + lrelu(gc.y + r.y) * a.y;
    float td = lrelu(gd.x + r.x) * a.x + lrelu(gd.y + r.y) * a.y;
#pragma unroll
    for (int o = 4; o; o >>= 1) {
      ta += __shfl_xor(ta, o);
      tb += __shfl_xor(tb, o);
      tc += __shfl_xor(tc, o);
      td += __shfl_xor(td, o);
    }
    float ea = __expf(fminf(ta - m0, 60.f));
    float eb = __expf(fminf(tb - m0, 60.f));
    float ec = __expf(fminf(tc - m0, 60.f));
    float ed = __expf(fminf(td - m0, 60.f));
    den0 += ea; acc0.x += ea * ga.x; acc0.y += ea * ga.y;
    den1 += eb; acc1.x += eb * gb.x; acc1.y += eb * gb.y;
    den2 += ec; acc2.x += ec * gc.x; acc2.y += ec * gc.y;
    den3 += ed; acc3.x += ed * gd.x; acc3.y += ed * gd.y;
  }
  for (; i < i1; i++) {
    int s = csr_src[i];
    ushort2 va = ((const ushort2*)(xlb + (size_t)s * DD))[lane];
    float2 ga = {b2f(va.x), b2f(va.y)};
    float ta = lrelu(ga.x + r.x) * a.x + lrelu(ga.y + r.y) * a.y;
#pragma unroll
    for (int o = 4; o; o >>= 1) ta += __shfl_xor(ta, o);
    float ea = __expf(fminf(ta - m0, 60.f));
    den0 += ea;
    acc0.x += ea * ga.x;
    acc0.y += ea * ga.y;
  }
  float den = ((den0 + den1) + (den2 + den3)) + 1e-16f;
  float ax = (acc0.x + acc1.x) + (acc2.x + acc3.x);
  float ay = (acc0.y + acc1.y) + (acc2.y + acc3.y);
  float2 c = ((const float2*)cb)[lane];
  float inv = 1.f / den;
  ushort2 o2;
  o2.x = f2b(fmaxf(fmaf(ax, inv, c.x), 0.f));
  o2.y = f2b(fmaxf(fmaf(ay, inv, c.y), 0.f));
  ((ushort2*)(hfb + (size_t)d * DD))[lane] = o2;
}

// ---------- BN stats: uint4 loads, 8 ch/lane, two-stage reduce ----------
__global__ __launch_bounds__(256) void k_hbn2(const ushort* __restrict__ hfb,
    float* __restrict__ bnsum, int N) {
  int cg = threadIdx.x & 15;   // channel group: ch = cg*8 .. cg*8+7
  int rr = threadIdx.x >> 4;   // 16 rows in flight per block
  float s[8] = {}, ss[8] = {};
  for (int r = blockIdx.x * 16 + rr; r < N; r += gridDim.x * 16) {
    uint4 v = *(const uint4*)(hfb + (size_t)r * DD + cg * 8);
    float f;
    f = __uint_as_float(v.x << 16);          s[0] += f; ss[0] += f * f;
    f = __uint_as_float(v.x & 0xffff0000u);  s[1] += f; ss[1] += f * f;
    f = __uint_as_float(v.y << 16);          s[2] += f; ss[2] += f * f;
    f = __uint_as_float(v.y & 0xffff0000u);  s[3] += f; ss[3] += f * f;
    f = __uint_as_float(v.z << 16);          s[4] += f; ss[4] += f * f;
    f = __uint_as_float(v.z & 0xffff0000u);  s[5] += f; ss[5] += f * f;
    f = __uint_as_float(v.w << 16);          s[6] += f; ss[6] += f * f;
    f = __uint_as_float(v.w & 0xffff0000u);  s[7] += f; ss[7] += f * f;
  }
  __shared__ float ls[256][8];
#pragma unroll
  for (int j = 0; j < 8; j++) ls[threadIdx.x][j] = s[j];
  __syncthreads();
  if (rr == 0) {
    float t1[8] = {};
    for (int k = 0; k < 16; k++)
#pragma unroll
      for (int j = 0; j < 8; j++) t1[j] += ls[k * 16 + cg][j];
#pragma unroll
    for (int j = 0; j < 8; j++) atomAddF(&bnsum[cg * 8 + j], t1[j]);
  }
  __syncthreads();
#pragma unroll
  for (int j = 0; j < 8; j++) ls[threadIdx.x][j] = ss[j];
  __syncthreads();
  if (rr == 0) {
    float t1[8] = {};
    for (int k = 0; k < 16; k++)
#pragma unroll
      for (int j = 0; j < 8; j++) t1[j] += ls[k * 16 + cg][j];
#pragma unroll
    for (int j = 0; j < 8; j++) atomAddF(&bnsum[DD + cg * 8 + j], t1[j]);
  }
}

// ---------- fused fold: BN scale/shift + b1'/b2'' + W1P/W2P packs ----------
// Every block recomputes scale from bnsum locally (cheap) -> no cross-block dep.
__global__ __launch_bounds__(256) void k_fold(const float* __restrict__ bnsum,
    const float* __restrict__ gamma, const float* __restrict__ beta,
    const float* __restrict__ linW, const float* __restrict__ linb,
    const float* __restrict__ dec2W, const float* __restrict__ dec2b,
    float* __restrict__ b1p, float* __restrict__ b2pp,
    ushort* __restrict__ W1P, ushort* __restrict__ W2P, int N) {
  int b = blockIdx.x;
  float invN = 1.f / (float)N;
  if (b == 0) {
    int t = threadIdx.x;
    __shared__ float sshift[DD], sb1[DD];
    if (t < DD) {
      float mean = bnsum[t] * invN;
      float var = bnsum[DD + t] * invN - mean * mean;
      float sc = gamma[t] / sqrtf(var + 1e-5f);
      sshift[t] = beta[t] - mean * sc;
    }
    __syncthreads();
    if (t < DD) {
      float b1 = linb[t];
#pragma unroll 8
      for (int k = 0; k < DD; k++) b1 += sshift[k] * linW[k * DD + t];
      b1p[t] = b1;
      sb1[t] = b1;
    }
    __syncthreads();
    if (t < DD) {
      float b2v = dec2b[t];
#pragma unroll 8
      for (int k = 0; k < DD; k++) b2v += sb1[k] * dec2W[k * DD + t];
      b2pp[t] = b2v;
    }
  } else if (b <= 64) {  // W2P: pack scale[k] * (linW @ dec2W)[k][n]
    int i = (b - 1) * 256 + threadIdx.x;
    int k, n;
    packW_idx(i, k, n);
    float mean = bnsum[k] * invN;
    float var = bnsum[DD + k] * invN - mean * mean;
    float sc = gamma[k] / sqrtf(var + 1e-5f);
    float s = 0.f;
#pragma unroll 8
    for (int kk = 0; kk < DD; kk++) s += linW[k * DD + kk] * dec2W[kk * DD + n];
    W2P[i] = f2b(sc * s);
  } else {  // blocks 65..128, W1P: pack scale[k] * linW[k][n]
    int i = (b - 65) * 256 + threadIdx.x;
    int k, n;
    packW_idx(i, k, n);
    float mean = bnsum[k] * invN;
    float var = bnsum[DD + k] * invN - mean * mean;
    float sc = gamma[k] / sqrtf(var + 1e-5f);
    W1P[i] = f2b(sc * linW[k * DD + n]);
  }
}

// ---------- edge decoder: 4 edges/wave, 16 lanes x 8ch, packed bf16 ----------
__global__ __launch_bounds__(256) void k_edge(const ushort* __restrict__ zb,
    const int* __restrict__ ei, const float* __restrict__ ae,
    const float* __restrict__ be, float* __restrict__ v1, int E) {
  int lane = threadIdx.x & 63;
  int sub = lane >> 4;
  int cl = lane & 15;
  int wid = (blockIdx.x * 256 + threadIdx.x) >> 6;
  int nw = (gridDim.x * 256) >> 6;
  int nq = (E + 3) >> 2;
  float a = fmaxf(ae[0], 0.f), b = be[0];
  for (int q = wid; q < nq; q += nw) {
    int e = q * 4 + sub;
    bool ok = e < E;
    int ec = ok ? e : 0;
    int s = ei[ec], d = ei[E + ec];
    uint4 zs = *(const uint4*)(zb + (size_t)s * DD + cl * 8);
    uint4 zd = *(const uint4*)(zb + (size_t)d * DD + cl * 8);
    float v = 0.f;
    float dl, dh;
    dl = __uint_as_float(zs.x << 16) - __uint_as_float(zd.x << 16);
    dh = __uint_as_float(zs.x & 0xffff0000u) - __uint_as_float(zd.x & 0xffff0000u);
    v += dl * dl + dh * dh;
    dl = __uint_as_float(zs.y << 16) - __uint_as_float(zd.y << 16);
    dh = __uint_as_float(zs.y & 0xffff0000u) - __uint_as_float(zd.y & 0xffff0000u);
    v += dl * dl + dh * dh;
    dl = __uint_as_float(zs.z << 16) - __uint_as_float(zd.z << 16);
    dh = __uint_as_float(zs.z & 0xffff0000u) - __uint_as_float(zd.z & 0xffff0000u);
    v += dl * dl + dh * dh;
    dl = __uint_as_float(zs.w << 16) - __uint_as_float(zd.w << 16);
    dh = __uint_as_float(zs.w & 0xffff0000u) - __uint_as_float(zd.w & 0xffff0000u);
    v += dl * dl + dh * dh;
#pragma unroll
    for (int o = 8; o; o >>= 1) v += __shfl_xor(v, o);
    if (cl == 0 && ok) v1[e] = 1.f / (1.f + __expf(fmaf(a, v, b)));
  }
}

extern "C" void kernel_launch(void* const* d_in, const int* in_sizes, int n_in,
                              void* d_out, int out_size, void* d_ws, size_t ws_size,
                              hipStream_t stream) {
  const float* x = (const float*)d_in[0];
  const int* ei = (const int*)d_in[1];
  const float* Wl = (const float*)d_in[2];
  const float* bl = (const float*)d_in[3];
  const float* Wr = (const float*)d_in[4];
  const float* br = (const float*)d_in[5];
  const float* att = (const float*)d_in[6];
  const float* cb = (const float*)d_in[7];
  const float* gamma = (const float*)d_in[8];
  const float* beta = (const float*)d_in[9];
  const float* linW = (const float*)d_in[10];
  const float* linb = (const float*)d_in[11];
  const float* ae = (const float*)d_in[12];
  const float* be = (const float*)d_in[13];
  const float* dec2W = (const float*)d_in[14];
  const float* dec2b = (const float*)d_in[15];

  int N = in_sizes[0] / DD;
  int E = in_sizes[1] / 2;
  size_t ND = (size_t)N * DD;
  int B = (N + 255) / 256;

  char* wsb = (char*)d_ws;
  size_t o = 0;
  auto alloc = [&](size_t bytes) {
    void* p = wsb + o;
    o += (bytes + 15) & ~(size_t)15;
    return p;
  };
  ushort* xb  = (ushort*)alloc(ND * 2);
  ushort* xlb = (ushort*)alloc(ND * 2);
  ushort* xrb = (ushort*)alloc(ND * 2);
  ushort* hfb = (ushort*)alloc(ND * 2);
  ushort* zbb = (ushort*)alloc(ND * 2);
  ushort* WlP = (ushort*)alloc(DD * DD * 2);
  ushort* WrP = (ushort*)alloc(DD * DD * 2);
  ushort* W1P = (ushort*)alloc(DD * DD * 2);
  ushort* W2P = (ushort*)alloc(DD * DD * 2);
  float* b1p   = (float*)alloc(DD * 4);
  float* b2pp  = (float*)alloc(DD * 4);
  // deg + bnsum contiguous -> single memset
  int* deg      = (int*)alloc((size_t)(N + 1) * 4);
  float* bnsum  = (float*)alloc(2 * DD * 4);
  size_t clearBytes = (char*)(bnsum + 2 * DD) - (char*)deg;
  int* rowstart = (int*)alloc((size_t)(N + 1) * 4);
  int* cursor   = (int*)alloc((size_t)N * 4);
  int* bsum     = (int*)alloc((size_t)B * 4);
  int* boff     = (int*)alloc((size_t)B * 4);
  int* csr_src  = (int*)alloc((size_t)E * 4);

  float* z = (float*)d_out;
  float* v1 = z + ND;
  float* v2 = v1 + E;

  hipMemsetAsync(deg, 0, clearBytes, stream);

  int total4 = (int)(ND / 4);
  int convB = (total4 + 255) / 256;
  int packB = 128;
  int degB = (E + 255) / 256;
  k_prep<<<convB + packB + degB, 256, 0, stream>>>(x, xb, total4, Wl, Wr, WlP,
                                                   WrP, ei, deg, E, convB, packB);
  k_part<<<B, 256, 0, stream>>>(deg, rowstart, bsum, N);
  k_mid<<<1, 1024, 0, stream>>>(bsum, boff, rowstart + N, B);
  k_apply<<<B, 256, 0, stream>>>(rowstart, cursor, boff, N);
  k_fill<<<(E + 255) / 256, 256, 0, stream>>>(ei, cursor, csr_src, E);
  k_mm_lr<<<(N + 63) / 64, 256, 0, stream>>>(xb, WlP, WrP, bl, br, xlb, xrb, N);
  k_agg<<<(N + 3) / 4, 256, 0, stream>>>(xlb, xrb, rowstart, csr_src, att, cb,
                                         hfb, N);
  k_hbn2<<<256, 256, 0, stream>>>(hfb, bnsum, N);
  k_fold<<<129, 256, 0, stream>>>(bnsum, gamma, beta, linW, linb, dec2W, dec2b,
                                  b1p, b2pp, W1P, W2P, N);
  k_mm_z<<<(N + 63) / 64, 256, 0, stream>>>(hfb, W1P, W2P, b1p, b2pp, z, zbb,
                                            v2, N);
  k_edge<<<2048, 256, 0, stream>>>(zbb, ei, ae, be, v1, E);
}

// Round 7
// 281.951 us; speedup vs baseline: 1.1151x; 1.1151x over previous
//
#include <hip/hip_runtime.h>

#define DD 128
#define HH 8

typedef float f32x4 __attribute__((ext_vector_type(4)));
typedef short s16x8 __attribute__((ext_vector_type(8)));

__device__ __forceinline__ ushort f2b(float f) {
  unsigned u = __float_as_uint(f);
  unsigned r = u + 0x7fffu + ((u >> 16) & 1u);
  return (ushort)(r >> 16);
}
__device__ __forceinline__ float b2f(ushort b) {
  return __uint_as_float(((unsigned)b) << 16);
}
__device__ __forceinline__ void atomAddF(float* p, float v) {
#if defined(__HIP_DEVICE_COMPILE__)
  unsafeAtomicAdd(p, v);
#else
  atomicAdd(p, v);
#endif
}
__device__ __forceinline__ float lrelu(float v) { return fmaxf(v, 0.2f * v); }

// sum the 8 interleaved bnsum copies
__device__ __forceinline__ float sum8(const float* __restrict__ b8, int idx) {
  float s = 0.f;
#pragma unroll
  for (int c = 0; c < 8; c++) s += b8[(c << 8) + idx];
  return s;
}

// pack W[k][n] (128x128 row-major) into B-fragment order for 16x16x32 MFMA:
// P[((q*8+c)*64 + l)*8 + j] = W[q*32 + (l>>4)*8 + j][c*16 + (l&15)]
__device__ __forceinline__ void packW_idx(int i, int& k, int& n) {
  int j = i & 7, l = (i >> 3) & 63, tile = i >> 9;
  int q = tile >> 3, c = tile & 7;
  k = q * 32 + ((l >> 4) << 3) + j;
  n = c * 16 + (l & 15);
}

// ---------- fused prep: x->bf16 conv, Wl/Wr pack, degree histogram ----------
__global__ __launch_bounds__(256) void k_prep(const float* __restrict__ x,
    ushort* __restrict__ xb, int total4, const float* __restrict__ Wl,
    const float* __restrict__ Wr, ushort* __restrict__ WlP,
    ushort* __restrict__ WrP, const int* __restrict__ ei,
    int* __restrict__ deg, int E, int convB, int packB) {
  int b = blockIdx.x;
  if (b < convB) {
    int i = b * 256 + threadIdx.x;
    if (i < total4) {
      float4 v = ((const float4*)x)[i];
      ushort4 o;
      o.x = f2b(v.x); o.y = f2b(v.y); o.z = f2b(v.z); o.w = f2b(v.w);
      ((ushort4*)xb)[i] = o;
    }
  } else if (b < convB + packB) {
    int t = (b - convB) * 256 + threadIdx.x;  // 0..32767
    int side = t >> 14;
    int i = t & 16383;
    int k, n;
    packW_idx(i, k, n);
    if (side) WrP[i] = f2b(Wr[k * DD + n]);
    else      WlP[i] = f2b(Wl[k * DD + n]);
  } else {
    int e = (b - convB - packB) * 256 + threadIdx.x;
    if (e < E) atomicAdd(&deg[ei[E + e]], 1);
  }
}

// ---------- CSR scan ----------
__global__ __launch_bounds__(256) void k_part(const int* __restrict__ deg,
    int* __restrict__ rowstart, int* __restrict__ bsum, int N) {
  __shared__ int sc[256];
  int t = threadIdx.x;
  int i = blockIdx.x * 256 + t;
  int v = (i < N) ? deg[i] : 0;
  sc[t] = v;
  __syncthreads();
  for (int off = 1; off < 256; off <<= 1) {
    int u = (t >= off) ? sc[t - off] : 0;
    __syncthreads();
    sc[t] += u;
    __syncthreads();
  }
  if (i < N) rowstart[i] = sc[t] - v;
  if (t == 255) bsum[blockIdx.x] = sc[255];
}

__global__ __launch_bounds__(1024) void k_mid(const int* __restrict__ bsum,
    int* __restrict__ boff, int* __restrict__ rowstartN, int B) {
  __shared__ int sc[1024];
  int t = threadIdx.x;
  int v = (t < B) ? bsum[t] : 0;
  sc[t] = v;
  __syncthreads();
  for (int off = 1; off < 1024; off <<= 1) {
    int u = (t >= off) ? sc[t - off] : 0;
    __syncthreads();
    sc[t] += u;
    __syncthreads();
  }
  if (t < B) boff[t] = sc[t] - v;
  if (t == 1023) *rowstartN = sc[1023];
}

__global__ __launch_bounds__(256) void k_apply(int* __restrict__ rowstart,
    int* __restrict__ cursor, const int* __restrict__ boff, int N) {
  int i = blockIdx.x * 256 + threadIdx.x;
  if (i < N) {
    int r = rowstart[i] + boff[blockIdx.x];
    rowstart[i] = r;
    cursor[i] = r;
  }
}

__global__ __launch_bounds__(256) void k_fill(const int* __restrict__ ei,
    int* __restrict__ cursor, int* __restrict__ csr_src, int E) {
  int e = blockIdx.x * 256 + threadIdx.x;
  if (e < E) {
    int d = ei[E + e];
    int pos = atomicAdd(&cursor[d], 1);
    csr_src[pos] = ei[e];
  }
}

// ---------- MFMA GEMM: out_l/out_r (bf16) = A @ Wl/Wr + bias ----------
__global__ __launch_bounds__(256) void k_mm_lr(const ushort* __restrict__ xb,
    const ushort* __restrict__ WlP, const ushort* __restrict__ WrP,
    const float* __restrict__ bl, const float* __restrict__ br,
    ushort* __restrict__ xlb, ushort* __restrict__ xrb, int N) {
  __shared__ ushort sW[2][16384];
  {
    const uint4* a = (const uint4*)WlP;
    const uint4* b = (const uint4*)WrP;
    uint4* da = (uint4*)sW[0];
    uint4* db = (uint4*)sW[1];
    for (int i = threadIdx.x; i < 2048; i += 256) { da[i] = a[i]; db[i] = b[i]; }
  }
  __syncthreads();
  int lane = threadIdx.x & 63;
  int wv = threadIdx.x >> 6;
  int rbase = blockIdx.x * 64 + wv * 16;
  int arow = rbase + (lane & 15);
  if (arow >= N) arow = 0;  // stores masked below
  const ushort* ap = xb + (size_t)arow * DD + ((lane >> 4) << 3);
  s16x8 afr[4];
#pragma unroll
  for (int q = 0; q < 4; q++) afr[q] = *(const s16x8*)(ap + q * 32);
  f32x4 accL[8] = {}, accR[8] = {};
#pragma unroll
  for (int q = 0; q < 4; q++) {
#pragma unroll
    for (int c = 0; c < 8; c++) {
      s16x8 bL = *(const s16x8*)(sW[0] + ((q * 8 + c) * 64 + lane) * 8);
      accL[c] = __builtin_amdgcn_mfma_f32_16x16x32_bf16(afr[q], bL, accL[c], 0, 0, 0);
      s16x8 bR = *(const s16x8*)(sW[1] + ((q * 8 + c) * 64 + lane) * 8);
      accR[c] = __builtin_amdgcn_mfma_f32_16x16x32_bf16(afr[q], bR, accR[c], 0, 0, 0);
    }
  }
  int r0 = rbase + ((lane >> 4) << 2);
  int colb = lane & 15;
#pragma unroll
  for (int c = 0; c < 8; c++) {
    int col = c * 16 + colb;
    float vbl = bl[col], vbr = br[col];
#pragma unroll
    for (int r = 0; r < 4; r++) {
      int row = r0 + r;
      if (row < N) {
        xlb[(size_t)row * DD + col] = f2b(accL[c][r] + vbl);
        xrb[(size_t)row * DD + col] = f2b(accR[c][r] + vbr);
      }
    }
  }
}

// ---------- MFMA GEMM: z (f32 + bf16 copy) and v2 (f32) from hfeat ----------
__global__ __launch_bounds__(256) void k_mm_z(const ushort* __restrict__ hfb,
    const ushort* __restrict__ W1P, const ushort* __restrict__ W2P,
    const float* __restrict__ b1p, const float* __restrict__ b2pp,
    float* __restrict__ z, ushort* __restrict__ zb, float* __restrict__ v2,
    int N) {
  __shared__ ushort sW[2][16384];
  {
    const uint4* a = (const uint4*)W1P;
    const uint4* b = (const uint4*)W2P;
    uint4* da = (uint4*)sW[0];
    uint4* db = (uint4*)sW[1];
    for (int i = threadIdx.x; i < 2048; i += 256) { da[i] = a[i]; db[i] = b[i]; }
  }
  __syncthreads();
  int lane = threadIdx.x & 63;
  int wv = threadIdx.x >> 6;
  int rbase = blockIdx.x * 64 + wv * 16;
  int arow = rbase + (lane & 15);
  if (arow >= N) arow = 0;
  const ushort* ap = hfb + (size_t)arow * DD + ((lane >> 4) << 3);
  s16x8 afr[4];
#pragma unroll
  for (int q = 0; q < 4; q++) afr[q] = *(const s16x8*)(ap + q * 32);
  f32x4 acc1[8] = {}, acc2[8] = {};
#pragma unroll
  for (int q = 0; q < 4; q++) {
#pragma unroll
    for (int c = 0; c < 8; c++) {
      s16x8 b1 = *(const s16x8*)(sW[0] + ((q * 8 + c) * 64 + lane) * 8);
      acc1[c] = __builtin_amdgcn_mfma_f32_16x16x32_bf16(afr[q], b1, acc1[c], 0, 0, 0);
      s16x8 b2 = *(const s16x8*)(sW[1] + ((q * 8 + c) * 64 + lane) * 8);
      acc2[c] = __builtin_amdgcn_mfma_f32_16x16x32_bf16(afr[q], b2, acc2[c], 0, 0, 0);
    }
  }
  int r0 = rbase + ((lane >> 4) << 2);
  int colb = lane & 15;
#pragma unroll
  for (int c = 0; c < 8; c++) {
    int col = c * 16 + colb;
    float vb1 = b1p[col], vb2 = b2pp[col];
#pragma unroll
    for (int r = 0; r < 4; r++) {
      int row = r0 + r;
      if (row < N) {
        float zv = acc1[c][r] + vb1;
        z[(size_t)row * DD + col] = zv;
        zb[(size_t)row * DD + col] = f2b(zv);
        v2[(size_t)row * DD + col] = acc2[c][r] + vb2;
      }
    }
  }
}

// ---------- GAT aggregation (grid-stride) + fused BN statistics ----------
// fixed-ref softmax: exp(t - t_self)/sum, exact by shift invariance.
// Per-lane stat accumulators are 4 NAMED scalars (no arrays -> no scratch).
__global__ __launch_bounds__(256) void k_agg(const ushort* __restrict__ xlb,
    const ushort* __restrict__ xrb, const int* __restrict__ rowstart,
    const int* __restrict__ csr_src, const float* __restrict__ att,
    const float* __restrict__ cb, ushort* __restrict__ hfb,
    float* __restrict__ bnsum8, int N) {
  int lane = threadIdx.x & 63;
  int wv = threadIdx.x >> 6;
  int wid = (blockIdx.x * 256 + threadIdx.x) >> 6;
  int nw = (gridDim.x * 256) >> 6;
  float2 a = ((const float2*)att)[lane];
  float2 c = ((const float2*)cb)[lane];
  float sx = 0.f, sxx = 0.f, sy = 0.f, syy = 0.f;
  for (int d = wid; d < N; d += nw) {
    ushort2 rv = ((const ushort2*)(xrb + (size_t)d * DD))[lane];
    float2 r = {b2f(rv.x), b2f(rv.y)};
    // self loop seeds reference m0; e_self = exp(0) = 1
    ushort2 gv = ((const ushort2*)(xlb + (size_t)d * DD))[lane];
    float2 g0 = {b2f(gv.x), b2f(gv.y)};
    float t0 = lrelu(g0.x + r.x) * a.x + lrelu(g0.y + r.y) * a.y;
#pragma unroll
    for (int o = 4; o; o >>= 1) t0 += __shfl_xor(t0, o);
    float m0 = t0;
    float den0 = 1.f, den1 = 0.f, den2 = 0.f, den3 = 0.f;
    float2 acc0 = g0, acc1 = {0.f, 0.f}, acc2 = {0.f, 0.f}, acc3 = {0.f, 0.f};
    int i0 = rowstart[d], i1 = rowstart[d + 1];
    int i = i0;
    for (; i + 4 <= i1; i += 4) {
      int s0 = csr_src[i], s1 = csr_src[i + 1];
      int s2 = csr_src[i + 2], s3 = csr_src[i + 3];
      ushort2 va = ((const ushort2*)(xlb + (size_t)s0 * DD))[lane];
      ushort2 vb = ((const ushort2*)(xlb + (size_t)s1 * DD))[lane];
      ushort2 vc = ((const ushort2*)(xlb + (size_t)s2 * DD))[lane];
      ushort2 vd = ((const ushort2*)(xlb + (size_t)s3 * DD))[lane];
      float2 ga = {b2f(va.x), b2f(va.y)};
      float2 gb = {b2f(vb.x), b2f(vb.y)};
      float2 gc = {b2f(vc.x), b2f(vc.y)};
      float2 gd = {b2f(vd.x), b2f(vd.y)};
      float ta = lrelu(ga.x + r.x) * a.x + lrelu(ga.y + r.y) * a.y;
      float tb = lrelu(gb.x + r.x) * a.x + lrelu(gb.y + r.y) * a.y;
      float tc = lrelu(gc.x + r.x) * a.x + lrelu(gc.y + r.y) * a.y;
      float td = lrelu(gd.x + r.x) * a.x + lrelu(gd.y + r.y) * a.y;
#pragma unroll
      for (int o = 4; o; o >>= 1) {
        ta += __shfl_xor(ta, o);
        tb += __shfl_xor(tb, o);
        tc += __shfl_xor(tc, o);
        td += __shfl_xor(td, o);
      }
      float ea = __expf(fminf(ta - m0, 60.f));
      float eb = __expf(fminf(tb - m0, 60.f));
      float ec = __expf(fminf(tc - m0, 60.f));
      float ed = __expf(fminf(td - m0, 60.f));
      den0 += ea; acc0.x += ea * ga.x; acc0.y += ea * ga.y;
      den1 += eb; acc1.x += eb * gb.x; acc1.y += eb * gb.y;
      den2 += ec; acc2.x += ec * gc.x; acc2.y += ec * gc.y;
      den3 += ed; acc3.x += ed * gd.x; acc3.y += ed * gd.y;
    }
    for (; i < i1; i++) {
      int s = csr_src[i];
      ushort2 va = ((const ushort2*)(xlb + (size_t)s * DD))[lane];
      float2 ga = {b2f(va.x), b2f(va.y)};
      float ta = lrelu(ga.x + r.x) * a.x + lrelu(ga.y + r.y) * a.y;
#pragma unroll
      for (int o = 4; o; o >>= 1) ta += __shfl_xor(ta, o);
      float ea = __expf(fminf(ta - m0, 60.f));
      den0 += ea;
      acc0.x += ea * ga.x;
      acc0.y += ea * ga.y;
    }
    float den = ((den0 + den1) + (den2 + den3)) + 1e-16f;
    float ax = (acc0.x + acc1.x) + (acc2.x + acc3.x);
    float ay = (acc0.y + acc1.y) + (acc2.y + acc3.y);
    float inv = 1.f / den;
    float vx = fmaxf(fmaf(ax, inv, c.x), 0.f);
    float vy = fmaxf(fmaf(ay, inv, c.y), 0.f);
    sx += vx; sxx += vx * vx;
    sy += vy; syy += vy * vy;
    ushort2 o2;
    o2.x = f2b(vx);
    o2.y = f2b(vy);
    ((ushort2*)(hfb + (size_t)d * DD))[lane] = o2;
  }
  // block-level reduce of per-lane stats (4 waves) then 256 atomics/block
  __shared__ float4 red[4][64];
  red[wv][lane] = make_float4(sx, sxx, sy, syy);
  __syncthreads();
  if (wv == 0) {
    float4 p0 = red[0][lane], p1 = red[1][lane];
    float4 p2 = red[2][lane], p3 = red[3][lane];
    float* bs = bnsum8 + ((blockIdx.x & 7) << 8);
    atomAddF(&bs[2 * lane],           (p0.x + p1.x) + (p2.x + p3.x));
    atomAddF(&bs[2 * lane + 1],       (p0.z + p1.z) + (p2.z + p3.z));
    atomAddF(&bs[DD + 2 * lane],      (p0.y + p1.y) + (p2.y + p3.y));
    atomAddF(&bs[DD + 2 * lane + 1],  (p0.w + p1.w) + (p2.w + p3.w));
  }
}

// ---------- fused fold: BN scale/shift + b1'/b2'' + W1P/W2P packs ----------
__global__ __launch_bounds__(256) void k_fold(const float* __restrict__ bnsum8,
    const float* __restrict__ gamma, const float* __restrict__ beta,
    const float* __restrict__ linW, const float* __restrict__ linb,
    const float* __restrict__ dec2W, const float* __restrict__ dec2b,
    float* __restrict__ b1p, float* __restrict__ b2pp,
    ushort* __restrict__ W1P, ushort* __restrict__ W2P, int N) {
  int b = blockIdx.x;
  float invN = 1.f / (float)N;
  if (b == 0) {
    int t = threadIdx.x;
    __shared__ float sshift[DD], sb1[DD];
    if (t < DD) {
      float mean = sum8(bnsum8, t) * invN;
      float var = sum8(bnsum8, DD + t) * invN - mean * mean;
      float sc = gamma[t] / sqrtf(var + 1e-5f);
      sshift[t] = beta[t] - mean * sc;
    }
    __syncthreads();
    if (t < DD) {
      float b1 = linb[t];
#pragma unroll 8
      for (int k = 0; k < DD; k++) b1 += sshift[k] * linW[k * DD + t];
      b1p[t] = b1;
      sb1[t] = b1;
    }
    __syncthreads();
    if (t < DD) {
      float b2v = dec2b[t];
#pragma unroll 8
      for (int k = 0; k < DD; k++) b2v += sb1[k] * dec2W[k * DD + t];
      b2pp[t] = b2v;
    }
  } else if (b <= 64) {  // W2P: pack scale[k] * (linW @ dec2W)[k][n]
    int i = (b - 1) * 256 + threadIdx.x;
    int k, n;
    packW_idx(i, k, n);
    float mean = sum8(bnsum8, k) * invN;
    float var = sum8(bnsum8, DD + k) * invN - mean * mean;
    float sc = gamma[k] / sqrtf(var + 1e-5f);
    float s = 0.f;
#pragma unroll 8
    for (int kk = 0; kk < DD; kk++) s += linW[k * DD + kk] * dec2W[kk * DD + n];
    W2P[i] = f2b(sc * s);
  } else {  // blocks 65..128, W1P: pack scale[k] * linW[k][n]
    int i = (b - 65) * 256 + threadIdx.x;
    int k, n;
    packW_idx(i, k, n);
    float mean = sum8(bnsum8, k) * invN;
    float var = sum8(bnsum8, DD + k) * invN - mean * mean;
    float sc = gamma[k] / sqrtf(var + 1e-5f);
    W1P[i] = f2b(sc * linW[k * DD + n]);
  }
}

// ---------- edge decoder: 4 edges/wave, 16 lanes x 8ch, packed bf16 ----------
__global__ __launch_bounds__(256) void k_edge(const ushort* __restrict__ zb,
    const int* __restrict__ ei, const float* __restrict__ ae,
    const float* __restrict__ be, float* __restrict__ v1, int E) {
  int lane = threadIdx.x & 63;
  int sub = lane >> 4;
  int cl = lane & 15;
  int wid = (blockIdx.x * 256 + threadIdx.x) >> 6;
  int nw = (gridDim.x * 256) >> 6;
  int nq = (E + 3) >> 2;
  float a = fmaxf(ae[0], 0.f), b = be[0];
  for (int q = wid; q < nq; q += nw) {
    int e = q * 4 + sub;
    bool ok = e < E;
    int ec = ok ? e : 0;
    int s = ei[ec], d = ei[E + ec];
    uint4 zs = *(const uint4*)(zb + (size_t)s * DD + cl * 8);
    uint4 zd = *(const uint4*)(zb + (size_t)d * DD + cl * 8);
    float v = 0.f;
    float dl, dh;
    dl = __uint_as_float(zs.x << 16) - __uint_as_float(zd.x << 16);
    dh = __uint_as_float(zs.x & 0xffff0000u) - __uint_as_float(zd.x & 0xffff0000u);
    v += dl * dl + dh * dh;
    dl = __uint_as_float(zs.y << 16) - __uint_as_float(zd.y << 16);
    dh = __uint_as_float(zs.y & 0xffff0000u) - __uint_as_float(zd.y & 0xffff0000u);
    v += dl * dl + dh * dh;
    dl = __uint_as_float(zs.z << 16) - __uint_as_float(zd.z << 16);
    dh = __uint_as_float(zs.z & 0xffff0000u) - __uint_as_float(zd.z & 0xffff0000u);
    v += dl * dl + dh * dh;
    dl = __uint_as_float(zs.w << 16) - __uint_as_float(zd.w << 16);
    dh = __uint_as_float(zs.w & 0xffff0000u) - __uint_as_float(zd.w & 0xffff0000u);
    v += dl * dl + dh * dh;
#pragma unroll
    for (int o = 8; o; o >>= 1) v += __shfl_xor(v, o);
    if (cl == 0 && ok) v1[e] = 1.f / (1.f + __expf(fmaf(a, v, b)));
  }
}

extern "C" void kernel_launch(void* const* d_in, const int* in_sizes, int n_in,
                              void* d_out, int out_size, void* d_ws, size_t ws_size,
                              hipStream_t stream) {
  const float* x = (const float*)d_in[0];
  const int* ei = (const int*)d_in[1];
  const float* Wl = (const float*)d_in[2];
  const float* bl = (const float*)d_in[3];
  const float* Wr = (const float*)d_in[4];
  const float* br = (const float*)d_in[5];
  const float* att = (const float*)d_in[6];
  const float* cb = (const float*)d_in[7];
  const float* gamma = (const float*)d_in[8];
  const float* beta = (const float*)d_in[9];
  const float* linW = (const float*)d_in[10];
  const float* linb = (const float*)d_in[11];
  const float* ae = (const float*)d_in[12];
  const float* be = (const float*)d_in[13];
  const float* dec2W = (const float*)d_in[14];
  const float* dec2b = (const float*)d_in[15];

  int N = in_sizes[0] / DD;
  int E = in_sizes[1] / 2;
  size_t ND = (size_t)N * DD;
  int B = (N + 255) / 256;

  char* wsb = (char*)d_ws;
  size_t o = 0;
  auto alloc = [&](size_t bytes) {
    void* p = wsb + o;
    o += (bytes + 15) & ~(size_t)15;
    return p;
  };
  ushort* xb  = (ushort*)alloc(ND * 2);
  ushort* xlb = (ushort*)alloc(ND * 2);
  ushort* xrb = (ushort*)alloc(ND * 2);
  ushort* hfb = (ushort*)alloc(ND * 2);
  ushort* zbb = (ushort*)alloc(ND * 2);
  ushort* WlP = (ushort*)alloc(DD * DD * 2);
  ushort* WrP = (ushort*)alloc(DD * DD * 2);
  ushort* W1P = (ushort*)alloc(DD * DD * 2);
  ushort* W2P = (ushort*)alloc(DD * DD * 2);
  float* b1p   = (float*)alloc(DD * 4);
  float* b2pp  = (float*)alloc(DD * 4);
  // deg + bnsum8 contiguous -> single memset
  int* deg       = (int*)alloc((size_t)(N + 1) * 4);
  float* bnsum8  = (float*)alloc(8 * 2 * DD * 4);
  size_t clearBytes = (char*)(bnsum8 + 8 * 2 * DD) - (char*)deg;
  int* rowstart = (int*)alloc((size_t)(N + 1) * 4);
  int* cursor   = (int*)alloc((size_t)N * 4);
  int* bsum     = (int*)alloc((size_t)B * 4);
  int* boff     = (int*)alloc((size_t)B * 4);
  int* csr_src  = (int*)alloc((size_t)E * 4);

  float* z = (float*)d_out;
  float* v1 = z + ND;
  float* v2 = v1 + E;

  hipMemsetAsync(deg, 0, clearBytes, stream);

  int total4 = (int)(ND / 4);
  int convB = (total4 + 255) / 256;
  int packB = 128;
  int degB = (E + 255) / 256;
  k_prep<<<convB + packB + degB, 256, 0, stream>>>(x, xb, total4, Wl, Wr, WlP,
                                                   WrP, ei, deg, E, convB, packB);
  k_part<<<B, 256, 0, stream>>>(deg, rowstart, bsum, N);
  k_mid<<<1, 1024, 0, stream>>>(bsum, boff, rowstart + N, B);
  k_apply<<<B, 256, 0, stream>>>(rowstart, cursor, boff, N);
  k_fill<<<(E + 255) / 256, 256, 0, stream>>>(ei, cursor, csr_src, E);
  k_mm_lr<<<(N + 63) / 64, 256, 0, stream>>>(xb, WlP, WrP, bl, br, xlb, xrb, N);
  k_agg<<<2048, 256, 0, stream>>>(xlb, xrb, rowstart, csr_src, att, cb, hfb,
                                  bnsum8, N);
  k_fold<<<129, 256, 0, stream>>>(bnsum8, gamma, beta, linW, linb, dec2W,
                                  dec2b, b1p, b2pp, W1P, W2P, N);
  k_mm_z<<<(N + 63) / 64, 256, 0, stream>>>(hfb, W1P, W2P, b1p, b2pp, z, zbb,
                                            v2, N);
  k_edge<<<2048, 256, 0, stream>>>(zbb, ei, ae, be, v1, E);
}

// Round 8
// 267.439 us; speedup vs baseline: 1.1756x; 1.0543x over previous
//
#include <hip/hip_runtime.h>

#define DD 128
#define HH 8
#define NBCOPY 32

typedef float f32x4 __attribute__((ext_vector_type(4)));
typedef short s16x8 __attribute__((ext_vector_type(8)));

__device__ __forceinline__ ushort f2b(float f) {
  unsigned u = __float_as_uint(f);
  unsigned r = u + 0x7fffu + ((u >> 16) & 1u);
  return (ushort)(r >> 16);
}
__device__ __forceinline__ float b2f(ushort b) {
  return __uint_as_float(((unsigned)b) << 16);
}
__device__ __forceinline__ void atomAddF(float* p, float v) {
#if defined(__HIP_DEVICE_COMPILE__)
  unsafeAtomicAdd(p, v);
#else
  atomicAdd(p, v);
#endif
}
__device__ __forceinline__ float lrelu(float v) { return fmaxf(v, 0.2f * v); }

// sum the NBCOPY interleaved bnsum copies
__device__ __forceinline__ float sumC(const float* __restrict__ b8, int idx) {
  float s = 0.f;
#pragma unroll
  for (int c = 0; c < NBCOPY; c++) s += b8[(c << 8) + idx];
  return s;
}

// pack W[k][n] (128x128 row-major) into B-fragment order for 16x16x32 MFMA:
// P[((q*8+c)*64 + l)*8 + j] = W[q*32 + (l>>4)*8 + j][c*16 + (l&15)]
__device__ __forceinline__ void packW_idx(int i, int& k, int& n) {
  int j = i & 7, l = (i >> 3) & 63, tile = i >> 9;
  int q = tile >> 3, c = tile & 7;
  k = q * 32 + ((l >> 4) << 3) + j;
  n = c * 16 + (l & 15);
}

// ---------- fused prep: x->bf16 conv, Wl/Wr pack, degree histogram ----------
__global__ __launch_bounds__(256) void k_prep(const float* __restrict__ x,
    ushort* __restrict__ xb, int total4, const float* __restrict__ Wl,
    const float* __restrict__ Wr, ushort* __restrict__ WlP,
    ushort* __restrict__ WrP, const int* __restrict__ ei,
    int* __restrict__ deg, int E, int convB, int packB) {
  int b = blockIdx.x;
  if (b < convB) {
    int i = b * 256 + threadIdx.x;
    if (i < total4) {
      float4 v = ((const float4*)x)[i];
      ushort4 o;
      o.x = f2b(v.x); o.y = f2b(v.y); o.z = f2b(v.z); o.w = f2b(v.w);
      ((ushort4*)xb)[i] = o;
    }
  } else if (b < convB + packB) {
    int t = (b - convB) * 256 + threadIdx.x;  // 0..32767
    int side = t >> 14;
    int i = t & 16383;
    int k, n;
    packW_idx(i, k, n);
    if (side) WrP[i] = f2b(Wr[k * DD + n]);
    else      WlP[i] = f2b(Wl[k * DD + n]);
  } else {
    int e = (b - convB - packB) * 256 + threadIdx.x;
    if (e < E) atomicAdd(&deg[ei[E + e]], 1);
  }
}

// ---------- CSR scan ----------
__global__ __launch_bounds__(256) void k_part(const int* __restrict__ deg,
    int* __restrict__ rowstart, int* __restrict__ bsum, int N) {
  __shared__ int sc[256];
  int t = threadIdx.x;
  int i = blockIdx.x * 256 + t;
  int v = (i < N) ? deg[i] : 0;
  sc[t] = v;
  __syncthreads();
  for (int off = 1; off < 256; off <<= 1) {
    int u = (t >= off) ? sc[t - off] : 0;
    __syncthreads();
    sc[t] += u;
    __syncthreads();
  }
  if (i < N) rowstart[i] = sc[t] - v;
  if (t == 255) bsum[blockIdx.x] = sc[255];
}

__global__ __launch_bounds__(1024) void k_mid(const int* __restrict__ bsum,
    int* __restrict__ boff, int* __restrict__ rowstartN, int B) {
  __shared__ int sc[1024];
  int t = threadIdx.x;
  int v = (t < B) ? bsum[t] : 0;
  sc[t] = v;
  __syncthreads();
  for (int off = 1; off < 1024; off <<= 1) {
    int u = (t >= off) ? sc[t - off] : 0;
    __syncthreads();
    sc[t] += u;
    __syncthreads();
  }
  if (t < B) boff[t] = sc[t] - v;
  if (t == 1023) *rowstartN = sc[1023];
}

__global__ __launch_bounds__(256) void k_apply(int* __restrict__ rowstart,
    int* __restrict__ cursor, const int* __restrict__ boff, int N) {
  int i = blockIdx.x * 256 + threadIdx.x;
  if (i < N) {
    int r = rowstart[i] + boff[blockIdx.x];
    rowstart[i] = r;
    cursor[i] = r;
  }
}

__global__ __launch_bounds__(256) void k_fill(const int* __restrict__ ei,
    int* __restrict__ cursor, int* __restrict__ csr_src, int E) {
  int e = blockIdx.x * 256 + threadIdx.x;
  if (e < E) {
    int d = ei[E + e];
    int pos = atomicAdd(&cursor[d], 1);
    csr_src[pos] = ei[e];
  }
}

// ---------- MFMA GEMM: out_l/out_r (bf16) = A @ Wl/Wr + bias ----------
__global__ __launch_bounds__(256) void k_mm_lr(const ushort* __restrict__ xb,
    const ushort* __restrict__ WlP, const ushort* __restrict__ WrP,
    const float* __restrict__ bl, const float* __restrict__ br,
    ushort* __restrict__ xlb, ushort* __restrict__ xrb, int N) {
  __shared__ ushort sW[2][16384];
  {
    const uint4* a = (const uint4*)WlP;
    const uint4* b = (const uint4*)WrP;
    uint4* da = (uint4*)sW[0];
    uint4* db = (uint4*)sW[1];
    for (int i = threadIdx.x; i < 2048; i += 256) { da[i] = a[i]; db[i] = b[i]; }
  }
  __syncthreads();
  int lane = threadIdx.x & 63;
  int wv = threadIdx.x >> 6;
  int rbase = blockIdx.x * 64 + wv * 16;
  int arow = rbase + (lane & 15);
  if (arow >= N) arow = 0;  // stores masked below
  const ushort* ap = xb + (size_t)arow * DD + ((lane >> 4) << 3);
  s16x8 afr[4];
#pragma unroll
  for (int q = 0; q < 4; q++) afr[q] = *(const s16x8*)(ap + q * 32);
  f32x4 accL[8] = {}, accR[8] = {};
#pragma unroll
  for (int q = 0; q < 4; q++) {
#pragma unroll
    for (int c = 0; c < 8; c++) {
      s16x8 bL = *(const s16x8*)(sW[0] + ((q * 8 + c) * 64 + lane) * 8);
      accL[c] = __builtin_amdgcn_mfma_f32_16x16x32_bf16(afr[q], bL, accL[c], 0, 0, 0);
      s16x8 bR = *(const s16x8*)(sW[1] + ((q * 8 + c) * 64 + lane) * 8);
      accR[c] = __builtin_amdgcn_mfma_f32_16x16x32_bf16(afr[q], bR, accR[c], 0, 0, 0);
    }
  }
  int r0 = rbase + ((lane >> 4) << 2);
  int colb = lane & 15;
#pragma unroll
  for (int c = 0; c < 8; c++) {
    int col = c * 16 + colb;
    float vbl = bl[col], vbr = br[col];
#pragma unroll
    for (int r = 0; r < 4; r++) {
      int row = r0 + r;
      if (row < N) {
        xlb[(size_t)row * DD + col] = f2b(accL[c][r] + vbl);
        xrb[(size_t)row * DD + col] = f2b(accR[c][r] + vbr);
      }
    }
  }
}

// ---------- MFMA GEMM: z (f32 + bf16 copy) and v2 (f32) from hfeat ----------
__global__ __launch_bounds__(256) void k_mm_z(const ushort* __restrict__ hfb,
    const ushort* __restrict__ W1P, const ushort* __restrict__ W2P,
    const float* __restrict__ b1p, const float* __restrict__ b2pp,
    float* __restrict__ z, ushort* __restrict__ zb, float* __restrict__ v2,
    int N) {
  __shared__ ushort sW[2][16384];
  {
    const uint4* a = (const uint4*)W1P;
    const uint4* b = (const uint4*)W2P;
    uint4* da = (uint4*)sW[0];
    uint4* db = (uint4*)sW[1];
    for (int i = threadIdx.x; i < 2048; i += 256) { da[i] = a[i]; db[i] = b[i]; }
  }
  __syncthreads();
  int lane = threadIdx.x & 63;
  int wv = threadIdx.x >> 6;
  int rbase = blockIdx.x * 64 + wv * 16;
  int arow = rbase + (lane & 15);
  if (arow >= N) arow = 0;
  const ushort* ap = hfb + (size_t)arow * DD + ((lane >> 4) << 3);
  s16x8 afr[4];
#pragma unroll
  for (int q = 0; q < 4; q++) afr[q] = *(const s16x8*)(ap + q * 32);
  f32x4 acc1[8] = {}, acc2[8] = {};
#pragma unroll
  for (int q = 0; q < 4; q++) {
#pragma unroll
    for (int c = 0; c < 8; c++) {
      s16x8 b1 = *(const s16x8*)(sW[0] + ((q * 8 + c) * 64 + lane) * 8);
      acc1[c] = __builtin_amdgcn_mfma_f32_16x16x32_bf16(afr[q], b1, acc1[c], 0, 0, 0);
      s16x8 b2 = *(const s16x8*)(sW[1] + ((q * 8 + c) * 64 + lane) * 8);
      acc2[c] = __builtin_amdgcn_mfma_f32_16x16x32_bf16(afr[q], b2, acc2[c], 0, 0, 0);
    }
  }
  int r0 = rbase + ((lane >> 4) << 2);
  int colb = lane & 15;
#pragma unroll
  for (int c = 0; c < 8; c++) {
    int col = c * 16 + colb;
    float vb1 = b1p[col], vb2 = b2pp[col];
#pragma unroll
    for (int r = 0; r < 4; r++) {
      int row = r0 + r;
      if (row < N) {
        float zv = acc1[c][r] + vb1;
        z[(size_t)row * DD + col] = zv;
        zb[(size_t)row * DD + col] = f2b(zv);
        v2[(size_t)row * DD + col] = acc2[c][r] + vb2;
      }
    }
  }
}

// ---------- GAT aggregation (1 node/wave) + fused BN statistics ----------
// fixed-ref softmax: exp(t - t_self)/sum, exact by shift invariance.
__global__ __launch_bounds__(256) void k_agg(const ushort* __restrict__ xlb,
    const ushort* __restrict__ xrb, const int* __restrict__ rowstart,
    const int* __restrict__ csr_src, const float* __restrict__ att,
    const float* __restrict__ cb, ushort* __restrict__ hfb,
    float* __restrict__ bnsumC, int N) {
  int lane = threadIdx.x & 63;
  int wv = threadIdx.x >> 6;
  int d = (blockIdx.x * 256 + threadIdx.x) >> 6;
  bool active = d < N;
  int dc = active ? d : 0;
  float2 a = ((const float2*)att)[lane];
  float2 c = ((const float2*)cb)[lane];
  float vx = 0.f, vy = 0.f;
  {
    ushort2 rv = ((const ushort2*)(xrb + (size_t)dc * DD))[lane];
    float2 r = {b2f(rv.x), b2f(rv.y)};
    // self loop seeds reference m0; e_self = exp(0) = 1
    ushort2 gv = ((const ushort2*)(xlb + (size_t)dc * DD))[lane];
    float2 g0 = {b2f(gv.x), b2f(gv.y)};
    float t0 = lrelu(g0.x + r.x) * a.x + lrelu(g0.y + r.y) * a.y;
#pragma unroll
    for (int o = 4; o; o >>= 1) t0 += __shfl_xor(t0, o);
    float m0 = t0;
    float den0 = 1.f, den1 = 0.f, den2 = 0.f, den3 = 0.f;
    float2 acc0 = g0, acc1 = {0.f, 0.f}, acc2 = {0.f, 0.f}, acc3 = {0.f, 0.f};
    int i0 = rowstart[dc], i1 = active ? rowstart[dc + 1] : i0;
    int i = i0;
    for (; i + 4 <= i1; i += 4) {
      int s0 = csr_src[i], s1 = csr_src[i + 1];
      int s2 = csr_src[i + 2], s3 = csr_src[i + 3];
      ushort2 va = ((const ushort2*)(xlb + (size_t)s0 * DD))[lane];
      ushort2 vb = ((const ushort2*)(xlb + (size_t)s1 * DD))[lane];
      ushort2 vc = ((const ushort2*)(xlb + (size_t)s2 * DD))[lane];
      ushort2 vd = ((const ushort2*)(xlb + (size_t)s3 * DD))[lane];
      float2 ga = {b2f(va.x), b2f(va.y)};
      float2 gb = {b2f(vb.x), b2f(vb.y)};
      float2 gc = {b2f(vc.x), b2f(vc.y)};
      float2 gd = {b2f(vd.x), b2f(vd.y)};
      float ta = lrelu(ga.x + r.x) * a.x + lrelu(ga.y + r.y) * a.y;
      float tb = lrelu(gb.x + r.x) * a.x + lrelu(gb.y + r.y) * a.y;
      float tc = lrelu(gc.x + r.x) * a.x + lrelu(gc.y + r.y) * a.y;
      float td = lrelu(gd.x + r.x) * a.x + lrelu(gd.y + r.y) * a.y;
#pragma unroll
      for (int o = 4; o; o >>= 1) {
        ta += __shfl_xor(ta, o);
        tb += __shfl_xor(tb, o);
        tc += __shfl_xor(tc, o);
        td += __shfl_xor(td, o);
      }
      float ea = __expf(fminf(ta - m0, 60.f));
      float eb = __expf(fminf(tb - m0, 60.f));
      float ec = __expf(fminf(tc - m0, 60.f));
      float ed = __expf(fminf(td - m0, 60.f));
      den0 += ea; acc0.x += ea * ga.x; acc0.y += ea * ga.y;
      den1 += eb; acc1.x += eb * gb.x; acc1.y += eb * gb.y;
      den2 += ec; acc2.x += ec * gc.x; acc2.y += ec * gc.y;
      den3 += ed; acc3.x += ed * gd.x; acc3.y += ed * gd.y;
    }
    for (; i < i1; i++) {
      int s = csr_src[i];
      ushort2 va = ((const ushort2*)(xlb + (size_t)s * DD))[lane];
      float2 ga = {b2f(va.x), b2f(va.y)};
      float ta = lrelu(ga.x + r.x) * a.x + lrelu(ga.y + r.y) * a.y;
#pragma unroll
      for (int o = 4; o; o >>= 1) ta += __shfl_xor(ta, o);
      float ea = __expf(fminf(ta - m0, 60.f));
      den0 += ea;
      acc0.x += ea * ga.x;
      acc0.y += ea * ga.y;
    }
    float den = ((den0 + den1) + (den2 + den3)) + 1e-16f;
    float ax = (acc0.x + acc1.x) + (acc2.x + acc3.x);
    float ay = (acc0.y + acc1.y) + (acc2.y + acc3.y);
    float inv = 1.f / den;
    if (active) {
      vx = fmaxf(fmaf(ax, inv, c.x), 0.f);
      vy = fmaxf(fmaf(ay, inv, c.y), 0.f);
      ushort2 o2;
      o2.x = f2b(vx);
      o2.y = f2b(vy);
      ((ushort2*)(hfb + (size_t)dc * DD))[lane] = o2;
    }
  }
  // block-level reduce of per-lane stats (4 waves) then 256 atomics/block
  __shared__ float4 red[4][64];
  red[wv][lane] = make_float4(vx, vx * vx, vy, vy * vy);
  __syncthreads();
  if (wv == 0) {
    float4 p0 = red[0][lane], p1 = red[1][lane];
    float4 p2 = red[2][lane], p3 = red[3][lane];
    float* bs = bnsumC + ((blockIdx.x & (NBCOPY - 1)) << 8);
    atomAddF(&bs[2 * lane],           (p0.x + p1.x) + (p2.x + p3.x));
    atomAddF(&bs[2 * lane + 1],       (p0.z + p1.z) + (p2.z + p3.z));
    atomAddF(&bs[DD + 2 * lane],      (p0.y + p1.y) + (p2.y + p3.y));
    atomAddF(&bs[DD + 2 * lane + 1],  (p0.w + p1.w) + (p2.w + p3.w));
  }
}

// ---------- fused fold: BN scale/shift + b1'/b2'' + W1P/W2P packs ----------
__global__ __launch_bounds__(256) void k_fold(const float* __restrict__ bnsumC,
    const float* __restrict__ gamma, const float* __restrict__ beta,
    const float* __restrict__ linW, const float* __restrict__ linb,
    const float* __restrict__ dec2W, const float* __restrict__ dec2b,
    float* __restrict__ b1p, float* __restrict__ b2pp,
    ushort* __restrict__ W1P, ushort* __restrict__ W2P, int N) {
  int b = blockIdx.x;
  float invN = 1.f / (float)N;
  if (b == 0) {
    int t = threadIdx.x;
    __shared__ float sshift[DD], sb1[DD];
    if (t < DD) {
      float mean = sumC(bnsumC, t) * invN;
      float var = sumC(bnsumC, DD + t) * invN - mean * mean;
      float sc = gamma[t] / sqrtf(var + 1e-5f);
      sshift[t] = beta[t] - mean * sc;
    }
    __syncthreads();
    if (t < DD) {
      float b1 = linb[t];
#pragma unroll 8
      for (int k = 0; k < DD; k++) b1 += sshift[k] * linW[k * DD + t];
      b1p[t] = b1;
      sb1[t] = b1;
    }
    __syncthreads();
    if (t < DD) {
      float b2v = dec2b[t];
#pragma unroll 8
      for (int k = 0; k < DD; k++) b2v += sb1[k] * dec2W[k * DD + t];
      b2pp[t] = b2v;
    }
  } else if (b <= 64) {  // W2P: pack scale[k] * (linW @ dec2W)[k][n]
    int i = (b - 1) * 256 + threadIdx.x;
    int k, n;
    packW_idx(i, k, n);
    float mean = sumC(bnsumC, k) * invN;
    float var = sumC(bnsumC, DD + k) * invN - mean * mean;
    float sc = gamma[k] / sqrtf(var + 1e-5f);
    float s = 0.f;
#pragma unroll 8
    for (int kk = 0; kk < DD; kk++) s += linW[k * DD + kk] * dec2W[kk * DD + n];
    W2P[i] = f2b(sc * s);
  } else {  // blocks 65..128, W1P: pack scale[k] * linW[k][n]
    int i = (b - 65) * 256 + threadIdx.x;
    int k, n;
    packW_idx(i, k, n);
    float mean = sumC(bnsumC, k) * invN;
    float var = sumC(bnsumC, DD + k) * invN - mean * mean;
    float sc = gamma[k] / sqrtf(var + 1e-5f);
    W1P[i] = f2b(sc * linW[k * DD + n]);
  }
}

// ---------- edge decoder: 4 edges/wave, 16 lanes x 8ch, packed bf16 ----------
__global__ __launch_bounds__(256) void k_edge(const ushort* __restrict__ zb,
    const int* __restrict__ ei, const float* __restrict__ ae,
    const float* __restrict__ be, float* __restrict__ v1, int E) {
  int lane = threadIdx.x & 63;
  int sub = lane >> 4;
  int cl = lane & 15;
  int wid = (blockIdx.x * 256 + threadIdx.x) >> 6;
  int nw = (gridDim.x * 256) >> 6;
  int nq = (E + 3) >> 2;
  float a = fmaxf(ae[0], 0.f), b = be[0];
  for (int q = wid; q < nq; q += nw) {
    int e = q * 4 + sub;
    bool ok = e < E;
    int ec = ok ? e : 0;
    int s = ei[ec], d = ei[E + ec];
    uint4 zs = *(const uint4*)(zb + (size_t)s * DD + cl * 8);
    uint4 zd = *(const uint4*)(zb + (size_t)d * DD + cl * 8);
    float v = 0.f;
    float dl, dh;
    dl = __uint_as_float(zs.x << 16) - __uint_as_float(zd.x << 16);
    dh = __uint_as_float(zs.x & 0xffff0000u) - __uint_as_float(zd.x & 0xffff0000u);
    v += dl * dl + dh * dh;
    dl = __uint_as_float(zs.y << 16) - __uint_as_float(zd.y << 16);
    dh = __uint_as_float(zs.y & 0xffff0000u) - __uint_as_float(zd.y & 0xffff0000u);
    v += dl * dl + dh * dh;
    dl = __uint_as_float(zs.z << 16) - __uint_as_float(zd.z << 16);
    dh = __uint_as_float(zs.z & 0xffff0000u) - __uint_as_float(zd.z & 0xffff0000u);
    v += dl * dl + dh * dh;
    dl = __uint_as_float(zs.w << 16) - __uint_as_float(zd.w << 16);
    dh = __uint_as_float(zs.w & 0xffff0000u) - __uint_as_float(zd.w & 0xffff0000u);
    v += dl * dl + dh * dh;
#pragma unroll
    for (int o = 8; o; o >>= 1) v += __shfl_xor(v, o);
    if (cl == 0 && ok) v1[e] = 1.f / (1.f + __expf(fmaf(a, v, b)));
  }
}

extern "C" void kernel_launch(void* const* d_in, const int* in_sizes, int n_in,
                              void* d_out, int out_size, void* d_ws, size_t ws_size,
                              hipStream_t stream) {
  const float* x = (const float*)d_in[0];
  const int* ei = (const int*)d_in[1];
  const float* Wl = (const float*)d_in[2];
  const float* bl = (const float*)d_in[3];
  const float* Wr = (const float*)d_in[4];
  const float* br = (const float*)d_in[5];
  const float* att = (const float*)d_in[6];
  const float* cb = (const float*)d_in[7];
  const float* gamma = (const float*)d_in[8];
  const float* beta = (const float*)d_in[9];
  const float* linW = (const float*)d_in[10];
  const float* linb = (const float*)d_in[11];
  const float* ae = (const float*)d_in[12];
  const float* be = (const float*)d_in[13];
  const float* dec2W = (const float*)d_in[14];
  const float* dec2b = (const float*)d_in[15];

  int N = in_sizes[0] / DD;
  int E = in_sizes[1] / 2;
  size_t ND = (size_t)N * DD;
  int B = (N + 255) / 256;

  char* wsb = (char*)d_ws;
  size_t o = 0;
  auto alloc = [&](size_t bytes) {
    void* p = wsb + o;
    o += (bytes + 15) & ~(size_t)15;
    return p;
  };
  ushort* xb  = (ushort*)alloc(ND * 2);
  ushort* xlb = (ushort*)alloc(ND * 2);
  ushort* xrb = (ushort*)alloc(ND * 2);
  ushort* hfb = (ushort*)alloc(ND * 2);
  ushort* zbb = (ushort*)alloc(ND * 2);
  ushort* WlP = (ushort*)alloc(DD * DD * 2);
  ushort* WrP = (ushort*)alloc(DD * DD * 2);
  ushort* W1P = (ushort*)alloc(DD * DD * 2);
  ushort* W2P = (ushort*)alloc(DD * DD * 2);
  float* b1p   = (float*)alloc(DD * 4);
  float* b2pp  = (float*)alloc(DD * 4);
  // deg + bnsumC contiguous -> single memset
  int* deg       = (int*)alloc((size_t)(N + 1) * 4);
  float* bnsumC  = (float*)alloc(NBCOPY * 2 * DD * 4);
  size_t clearBytes = (char*)(bnsumC + NBCOPY * 2 * DD) - (char*)deg;
  int* rowstart = (int*)alloc((size_t)(N + 1) * 4);
  int* cursor   = (int*)alloc((size_t)N * 4);
  int* bsum     = (int*)alloc((size_t)B * 4);
  int* boff     = (int*)alloc((size_t)B * 4);
  int* csr_src  = (int*)alloc((size_t)E * 4);

  float* z = (float*)d_out;
  float* v1 = z + ND;
  float* v2 = v1 + E;

  hipMemsetAsync(deg, 0, clearBytes, stream);

  int total4 = (int)(ND / 4);
  int convB = (total4 + 255) / 256;
  int packB = 128;
  int degB = (E + 255) / 256;
  k_prep<<<convB + packB + degB, 256, 0, stream>>>(x, xb, total4, Wl, Wr, WlP,
                                                   WrP, ei, deg, E, convB, packB);
  k_part<<<B, 256, 0, stream>>>(deg, rowstart, bsum, N);
  k_mid<<<1, 1024, 0, stream>>>(bsum, boff, rowstart + N, B);
  k_apply<<<B, 256, 0, stream>>>(rowstart, cursor, boff, N);
  k_fill<<<(E + 255) / 256, 256, 0, stream>>>(ei, cursor, csr_src, E);
  k_mm_lr<<<(N + 63) / 64, 256, 0, stream>>>(xb, WlP, WrP, bl, br, xlb, xrb, N);
  k_agg<<<(N + 3) / 4, 256, 0, stream>>>(xlb, xrb, rowstart, csr_src, att, cb,
                                         hfb, bnsumC, N);
  k_fold<<<129, 256, 0, stream>>>(bnsumC, gamma, beta, linW, linb, dec2W,
                                  dec2b, b1p, b2pp, W1P, W2P, N);
  k_mm_z<<<(N + 63) / 64, 256, 0, stream>>>(hfb, W1P, W2P, b1p, b2pp, z, zbb,
                                            v2, N);
  k_edge<<<2048, 256, 0, stream>>>(zbb, ei, ae, be, v1, E);
}

// Round 9
// 241.919 us; speedup vs baseline: 1.2996x; 1.1055x over previous
//
#include <hip/hip_runtime.h>

#define DD 128
#define HH 8
#define NBCOPY 32
#define PADS 4  // counters padded to 16 ints = 64B line

typedef float f32x4 __attribute__((ext_vector_type(4)));
typedef short s16x8 __attribute__((ext_vector_type(8)));

__device__ __forceinline__ ushort f2b(float f) {
  unsigned u = __float_as_uint(f);
  unsigned r = u + 0x7fffu + ((u >> 16) & 1u);
  return (ushort)(r >> 16);
}
__device__ __forceinline__ float b2f(ushort b) {
  return __uint_as_float(((unsigned)b) << 16);
}
__device__ __forceinline__ void atomAddF(float* p, float v) {
#if defined(__HIP_DEVICE_COMPILE__)
  unsafeAtomicAdd(p, v);
#else
  atomicAdd(p, v);
#endif
}
__device__ __forceinline__ float lrelu(float v) { return fmaxf(v, 0.2f * v); }

__device__ __forceinline__ float sumC(const float* __restrict__ b8, int idx) {
  float s = 0.f;
#pragma unroll
  for (int c = 0; c < NBCOPY; c++) s += b8[(c << 8) + idx];
  return s;
}

// pack W[k][n] (128x128 row-major) into B-fragment order for 16x16x32 MFMA:
// P[((q*8+c)*64 + l)*8 + j] = W[q*32 + (l>>4)*8 + j][c*16 + (l&15)]
__device__ __forceinline__ void packW_idx(int i, int& k, int& n) {
  int j = i & 7, l = (i >> 3) & 63, tile = i >> 9;
  int q = tile >> 3, c = tile & 7;
  k = q * 32 + ((l >> 4) << 3) + j;
  n = c * 16 + (l & 15);
}

// ---------- fused prep: x->bf16 conv, Wl/Wr pack, degree histogram ----------
__global__ __launch_bounds__(256) void k_prep(const float* __restrict__ x,
    ushort* __restrict__ xb, int total4, const float* __restrict__ Wl,
    const float* __restrict__ Wr, ushort* __restrict__ WlP,
    ushort* __restrict__ WrP, const int* __restrict__ ei,
    int* __restrict__ deg, int E, int convB, int packB) {
  int b = blockIdx.x;
  if (b < convB) {
    int i = b * 256 + threadIdx.x;
    if (i < total4) {
      float4 v = ((const float4*)x)[i];
      ushort4 o;
      o.x = f2b(v.x); o.y = f2b(v.y); o.z = f2b(v.z); o.w = f2b(v.w);
      ((ushort4*)xb)[i] = o;
    }
  } else if (b < convB + packB) {
    int t = (b - convB) * 256 + threadIdx.x;  // 0..32767
    int side = t >> 14;
    int i = t & 16383;
    int k, n;
    packW_idx(i, k, n);
    if (side) WrP[i] = f2b(Wr[k * DD + n]);
    else      WlP[i] = f2b(Wl[k * DD + n]);
  } else {
    int e = (b - convB - packB) * 256 + threadIdx.x;
    if (e < E) atomicAdd(&deg[ei[E + e] << PADS], 1);
  }
}

// ---------- CSR scan (deg padded) ----------
__global__ __launch_bounds__(256) void k_part(const int* __restrict__ deg,
    int* __restrict__ rowstart, int* __restrict__ bsum, int N) {
  __shared__ int sc[256];
  int t = threadIdx.x;
  int i = blockIdx.x * 256 + t;
  int v = (i < N) ? deg[i << PADS] : 0;
  sc[t] = v;
  __syncthreads();
  for (int off = 1; off < 256; off <<= 1) {
    int u = (t >= off) ? sc[t - off] : 0;
    __syncthreads();
    sc[t] += u;
    __syncthreads();
  }
  if (i < N) rowstart[i] = sc[t] - v;
  if (t == 255) bsum[blockIdx.x] = sc[255];
}

__global__ __launch_bounds__(1024) void k_mid(const int* __restrict__ bsum,
    int* __restrict__ boff, int* __restrict__ rowstartN, int B) {
  __shared__ int sc[1024];
  int t = threadIdx.x;
  int v = (t < B) ? bsum[t] : 0;
  sc[t] = v;
  __syncthreads();
  for (int off = 1; off < 1024; off <<= 1) {
    int u = (t >= off) ? sc[t - off] : 0;
    __syncthreads();
    sc[t] += u;
    __syncthreads();
  }
  if (t < B) boff[t] = sc[t] - v;
  if (t == 1023) *rowstartN = sc[1023];
}

__global__ __launch_bounds__(256) void k_apply(int* __restrict__ rowstart,
    int* __restrict__ cursor, const int* __restrict__ boff, int N) {
  int i = blockIdx.x * 256 + threadIdx.x;
  if (i < N) {
    int r = rowstart[i] + boff[blockIdx.x];
    rowstart[i] = r;
    cursor[i << PADS] = r;
  }
}

// ---------- fused: mm_lr (MFMA, weights from L2) + csr fill ----------
__global__ __launch_bounds__(256) void k_lrfill(const ushort* __restrict__ xb,
    const ushort* __restrict__ WlP, const ushort* __restrict__ WrP,
    const float* __restrict__ bl, const float* __restrict__ br,
    ushort* __restrict__ xlb, ushort* __restrict__ xrb, int N, int mmB,
    const int* __restrict__ ei, int* __restrict__ cursor,
    int* __restrict__ csr_src, int E) {
  if ((int)blockIdx.x >= mmB) {
    int e = ((int)blockIdx.x - mmB) * 256 + threadIdx.x;
    if (e < E) {
      int d = ei[E + e];
      int pos = atomicAdd(&cursor[d << PADS], 1);
      csr_src[pos] = ei[e];
    }
    return;
  }
  int lane = threadIdx.x & 63;
  int wv = threadIdx.x >> 6;
  int rbase = blockIdx.x * 64 + wv * 16;
  int arow = rbase + (lane & 15);
  if (arow >= N) arow = 0;  // stores masked below
  const ushort* ap = xb + (size_t)arow * DD + ((lane >> 4) << 3);
  s16x8 afr[4];
#pragma unroll
  for (int q = 0; q < 4; q++) afr[q] = *(const s16x8*)(ap + q * 32);
  const s16x8* BL = (const s16x8*)WlP;
  const s16x8* BR = (const s16x8*)WrP;
  f32x4 accL[8] = {}, accR[8] = {};
#pragma unroll
  for (int q = 0; q < 4; q++) {
#pragma unroll
    for (int c = 0; c < 8; c++) {
      accL[c] = __builtin_amdgcn_mfma_f32_16x16x32_bf16(
          afr[q], BL[(q * 8 + c) * 64 + lane], accL[c], 0, 0, 0);
      accR[c] = __builtin_amdgcn_mfma_f32_16x16x32_bf16(
          afr[q], BR[(q * 8 + c) * 64 + lane], accR[c], 0, 0, 0);
    }
  }
  int r0 = rbase + ((lane >> 4) << 2);
  int colb = lane & 15;
#pragma unroll
  for (int c = 0; c < 8; c++) {
    int col = c * 16 + colb;
    float vbl = bl[col], vbr = br[col];
#pragma unroll
    for (int r = 0; r < 4; r++) {
      int row = r0 + r;
      if (row < N) {
        xlb[(size_t)row * DD + col] = f2b(accL[c][r] + vbl);
        xrb[(size_t)row * DD + col] = f2b(accR[c][r] + vbr);
      }
    }
  }
}

// ---------- GAT aggregation (1 node/wave) + fused BN statistics ----------
__global__ __launch_bounds__(256) void k_agg(const ushort* __restrict__ xlb,
    const ushort* __restrict__ xrb, const int* __restrict__ rowstart,
    const int* __restrict__ csr_src, const float* __restrict__ att,
    const float* __restrict__ cb, ushort* __restrict__ hfb,
    float* __restrict__ bnsumC, int N) {
  int lane = threadIdx.x & 63;
  int wv = threadIdx.x >> 6;
  int d = (blockIdx.x * 256 + threadIdx.x) >> 6;
  bool active = d < N;
  int dc = active ? d : 0;
  float2 a = ((const float2*)att)[lane];
  float2 c = ((const float2*)cb)[lane];
  float vx = 0.f, vy = 0.f;
  {
    ushort2 rv = ((const ushort2*)(xrb + (size_t)dc * DD))[lane];
    float2 r = {b2f(rv.x), b2f(rv.y)};
    ushort2 gv = ((const ushort2*)(xlb + (size_t)dc * DD))[lane];
    float2 g0 = {b2f(gv.x), b2f(gv.y)};
    float t0 = lrelu(g0.x + r.x) * a.x + lrelu(g0.y + r.y) * a.y;
#pragma unroll
    for (int o = 4; o; o >>= 1) t0 += __shfl_xor(t0, o);
    float m0 = t0;
    float den0 = 1.f, den1 = 0.f, den2 = 0.f, den3 = 0.f;
    float2 acc0 = g0, acc1 = {0.f, 0.f}, acc2 = {0.f, 0.f}, acc3 = {0.f, 0.f};
    int i0 = rowstart[dc], i1 = active ? rowstart[dc + 1] : i0;
    int i = i0;
    for (; i + 4 <= i1; i += 4) {
      int s0 = csr_src[i], s1 = csr_src[i + 1];
      int s2 = csr_src[i + 2], s3 = csr_src[i + 3];
      ushort2 va = ((const ushort2*)(xlb + (size_t)s0 * DD))[lane];
      ushort2 vb = ((const ushort2*)(xlb + (size_t)s1 * DD))[lane];
      ushort2 vc = ((const ushort2*)(xlb + (size_t)s2 * DD))[lane];
      ushort2 vd = ((const ushort2*)(xlb + (size_t)s3 * DD))[lane];
      float2 ga = {b2f(va.x), b2f(va.y)};
      float2 gb = {b2f(vb.x), b2f(vb.y)};
      float2 gc = {b2f(vc.x), b2f(vc.y)};
      float2 gd = {b2f(vd.x), b2f(vd.y)};
      float ta = lrelu(ga.x + r.x) * a.x + lrelu(ga.y + r.y) * a.y;
      float tb = lrelu(gb.x + r.x) * a.x + lrelu(gb.y + r.y) * a.y;
      float tc = lrelu(gc.x + r.x) * a.x + lrelu(gc.y + r.y) * a.y;
      float td = lrelu(gd.x + r.x) * a.x + lrelu(gd.y + r.y) * a.y;
#pragma unroll
      for (int o = 4; o; o >>= 1) {
        ta += __shfl_xor(ta, o);
        tb += __shfl_xor(tb, o);
        tc += __shfl_xor(tc, o);
        td += __shfl_xor(td, o);
      }
      float ea = __expf(fminf(ta - m0, 60.f));
      float eb = __expf(fminf(tb - m0, 60.f));
      float ec = __expf(fminf(tc - m0, 60.f));
      float ed = __expf(fminf(td - m0, 60.f));
      den0 += ea; acc0.x += ea * ga.x; acc0.y += ea * ga.y;
      den1 += eb; acc1.x += eb * gb.x; acc1.y += eb * gb.y;
      den2 += ec; acc2.x += ec * gc.x; acc2.y += ec * gc.y;
      den3 += ed; acc3.x += ed * gd.x; acc3.y += ed * gd.y;
    }
    for (; i < i1; i++) {
      int s = csr_src[i];
      ushort2 va = ((const ushort2*)(xlb + (size_t)s * DD))[lane];
      float2 ga = {b2f(va.x), b2f(va.y)};
      float ta = lrelu(ga.x + r.x) * a.x + lrelu(ga.y + r.y) * a.y;
#pragma unroll
      for (int o = 4; o; o >>= 1) ta += __shfl_xor(ta, o);
      float ea = __expf(fminf(ta - m0, 60.f));
      den0 += ea;
      acc0.x += ea * ga.x;
      acc0.y += ea * ga.y;
    }
    float den = ((den0 + den1) + (den2 + den3)) + 1e-16f;
    float ax = (acc0.x + acc1.x) + (acc2.x + acc3.x);
    float ay = (acc0.y + acc1.y) + (acc2.y + acc3.y);
    float inv = 1.f / den;
    if (active) {
      vx = fmaxf(fmaf(ax, inv, c.x), 0.f);
      vy = fmaxf(fmaf(ay, inv, c.y), 0.f);
      ushort2 o2;
      o2.x = f2b(vx);
      o2.y = f2b(vy);
      ((ushort2*)(hfb + (size_t)dc * DD))[lane] = o2;
    }
  }
  __shared__ float4 red[4][64];
  red[wv][lane] = make_float4(vx, vx * vx, vy, vy * vy);
  __syncthreads();
  if (wv == 0) {
    float4 p0 = red[0][lane], p1 = red[1][lane];
    float4 p2 = red[2][lane], p3 = red[3][lane];
    float* bs = bnsumC + ((blockIdx.x & (NBCOPY - 1)) << 8);
    atomAddF(&bs[2 * lane],           (p0.x + p1.x) + (p2.x + p3.x));
    atomAddF(&bs[2 * lane + 1],       (p0.z + p1.z) + (p2.z + p3.z));
    atomAddF(&bs[DD + 2 * lane],      (p0.y + p1.y) + (p2.y + p3.y));
    atomAddF(&bs[DD + 2 * lane + 1],  (p0.w + p1.w) + (p2.w + p3.w));
  }
}

// ---------- fused fold: BN scale/shift + b1'/b2'' + W1P/W2P packs ----------
__global__ __launch_bounds__(256) void k_fold(const float* __restrict__ bnsumC,
    const float* __restrict__ gamma, const float* __restrict__ beta,
    const float* __restrict__ linW, const float* __restrict__ linb,
    const float* __restrict__ dec2W, const float* __restrict__ dec2b,
    float* __restrict__ b1p, float* __restrict__ b2pp,
    ushort* __restrict__ W1P, ushort* __restrict__ W2P, int N) {
  int b = blockIdx.x;
  float invN = 1.f / (float)N;
  if (b == 0) {
    int t = threadIdx.x;
    __shared__ float sshift[DD], sb1[DD];
    if (t < DD) {
      float mean = sumC(bnsumC, t) * invN;
      float var = sumC(bnsumC, DD + t) * invN - mean * mean;
      float sc = gamma[t] / sqrtf(var + 1e-5f);
      sshift[t] = beta[t] - mean * sc;
    }
    __syncthreads();
    if (t < DD) {
      float b1 = linb[t];
#pragma unroll 8
      for (int k = 0; k < DD; k++) b1 += sshift[k] * linW[k * DD + t];
      b1p[t] = b1;
      sb1[t] = b1;
    }
    __syncthreads();
    if (t < DD) {
      float b2v = dec2b[t];
#pragma unroll 8
      for (int k = 0; k < DD; k++) b2v += sb1[k] * dec2W[k * DD + t];
      b2pp[t] = b2v;
    }
  } else if (b <= 64) {
    int i = (b - 1) * 256 + threadIdx.x;
    int k, n;
    packW_idx(i, k, n);
    float mean = sumC(bnsumC, k) * invN;
    float var = sumC(bnsumC, DD + k) * invN - mean * mean;
    float sc = gamma[k] / sqrtf(var + 1e-5f);
    float s = 0.f;
#pragma unroll 8
    for (int kk = 0; kk < DD; kk++) s += linW[k * DD + kk] * dec2W[kk * DD + n];
    W2P[i] = f2b(sc * s);
  } else {
    int i = (b - 65) * 256 + threadIdx.x;
    int k, n;
    packW_idx(i, k, n);
    float mean = sumC(bnsumC, k) * invN;
    float var = sumC(bnsumC, DD + k) * invN - mean * mean;
    float sc = gamma[k] / sqrtf(var + 1e-5f);
    W1P[i] = f2b(sc * linW[k * DD + n]);
  }
}

// ---------- MFMA GEMM: z (f32) + zb (bf16) from hfeat, W1P from L2 ----------
__global__ __launch_bounds__(256) void k_mmz1(const ushort* __restrict__ hfb,
    const ushort* __restrict__ W1P, const float* __restrict__ b1p,
    float* __restrict__ z, ushort* __restrict__ zb, int N) {
  int lane = threadIdx.x & 63;
  int wv = threadIdx.x >> 6;
  int rbase = blockIdx.x * 64 + wv * 16;
  int arow = rbase + (lane & 15);
  if (arow >= N) arow = 0;
  const ushort* ap = hfb + (size_t)arow * DD + ((lane >> 4) << 3);
  s16x8 afr[4];
#pragma unroll
  for (int q = 0; q < 4; q++) afr[q] = *(const s16x8*)(ap + q * 32);
  const s16x8* B1 = (const s16x8*)W1P;
  f32x4 acc1[8] = {};
#pragma unroll
  for (int q = 0; q < 4; q++) {
#pragma unroll
    for (int c = 0; c < 8; c++) {
      acc1[c] = __builtin_amdgcn_mfma_f32_16x16x32_bf16(
          afr[q], B1[(q * 8 + c) * 64 + lane], acc1[c], 0, 0, 0);
    }
  }
  int r0 = rbase + ((lane >> 4) << 2);
  int colb = lane & 15;
#pragma unroll
  for (int c = 0; c < 8; c++) {
    int col = c * 16 + colb;
    float vb1 = b1p[col];
#pragma unroll
    for (int r = 0; r < 4; r++) {
      int row = r0 + r;
      if (row < N) {
        float zv = acc1[c][r] + vb1;
        z[(size_t)row * DD + col] = zv;
        zb[(size_t)row * DD + col] = f2b(zv);
      }
    }
  }
}

// ---------- fused tail: v2 GEMM + edge decoder ----------
__global__ __launch_bounds__(256) void k_v2edge(const ushort* __restrict__ hfb,
    const ushort* __restrict__ W2P, const float* __restrict__ b2pp,
    float* __restrict__ v2, int N, int v2B,
    const ushort* __restrict__ zb, const int* __restrict__ ei,
    const float* __restrict__ ae, const float* __restrict__ be,
    float* __restrict__ v1, int E, int edgeB) {
  if ((int)blockIdx.x < v2B) {
    int lane = threadIdx.x & 63;
    int wv = threadIdx.x >> 6;
    int rbase = blockIdx.x * 64 + wv * 16;
    int arow = rbase + (lane & 15);
    if (arow >= N) arow = 0;
    const ushort* ap = hfb + (size_t)arow * DD + ((lane >> 4) << 3);
    s16x8 afr[4];
#pragma unroll
    for (int q = 0; q < 4; q++) afr[q] = *(const s16x8*)(ap + q * 32);
    const s16x8* B2 = (const s16x8*)W2P;
    f32x4 acc2[8] = {};
#pragma unroll
    for (int q = 0; q < 4; q++) {
#pragma unroll
      for (int c = 0; c < 8; c++) {
        acc2[c] = __builtin_amdgcn_mfma_f32_16x16x32_bf16(
            afr[q], B2[(q * 8 + c) * 64 + lane], acc2[c], 0, 0, 0);
      }
    }
    int r0 = rbase + ((lane >> 4) << 2);
    int colb = lane & 15;
#pragma unroll
    for (int c = 0; c < 8; c++) {
      int col = c * 16 + colb;
      float vb2 = b2pp[col];
#pragma unroll
      for (int r = 0; r < 4; r++) {
        int row = r0 + r;
        if (row < N) v2[(size_t)row * DD + col] = acc2[c][r] + vb2;
      }
    }
    return;
  }
  int lane = threadIdx.x & 63;
  int sub = lane >> 4;
  int cl = lane & 15;
  int wid = (((int)blockIdx.x - v2B) * 256 + threadIdx.x) >> 6;
  int nw = (edgeB * 256) >> 6;
  int nq = (E + 3) >> 2;
  float a = fmaxf(ae[0], 0.f), b = be[0];
  for (int q = wid; q < nq; q += nw) {
    int e = q * 4 + sub;
    bool ok = e < E;
    int ec = ok ? e : 0;
    int s = ei[ec], d = ei[E + ec];
    uint4 zs = *(const uint4*)(zb + (size_t)s * DD + cl * 8);
    uint4 zd = *(const uint4*)(zb + (size_t)d * DD + cl * 8);
    float v = 0.f;
    float dl, dh;
    dl = __uint_as_float(zs.x << 16) - __uint_as_float(zd.x << 16);
    dh = __uint_as_float(zs.x & 0xffff0000u) - __uint_as_float(zd.x & 0xffff0000u);
    v += dl * dl + dh * dh;
    dl = __uint_as_float(zs.y << 16) - __uint_as_float(zd.y << 16);
    dh = __uint_as_float(zs.y & 0xffff0000u) - __uint_as_float(zd.y & 0xffff0000u);
    v += dl * dl + dh * dh;
    dl = __uint_as_float(zs.z << 16) - __uint_as_float(zd.z << 16);
    dh = __uint_as_float(zs.z & 0xffff0000u) - __uint_as_float(zd.z & 0xffff0000u);
    v += dl * dl + dh * dh;
    dl = __uint_as_float(zs.w << 16) - __uint_as_float(zd.w << 16);
    dh = __uint_as_float(zs.w & 0xffff0000u) - __uint_as_float(zd.w & 0xffff0000u);
    v += dl * dl + dh * dh;
#pragma unroll
    for (int o = 8; o; o >>= 1) v += __shfl_xor(v, o);
    if (cl == 0 && ok) v1[e] = 1.f / (1.f + __expf(fmaf(a, v, b)));
  }
}

extern "C" void kernel_launch(void* const* d_in, const int* in_sizes, int n_in,
                              void* d_out, int out_size, void* d_ws, size_t ws_size,
                              hipStream_t stream) {
  const float* x = (const float*)d_in[0];
  const int* ei = (const int*)d_in[1];
  const float* Wl = (const float*)d_in[2];
  const float* bl = (const float*)d_in[3];
  const float* Wr = (const float*)d_in[4];
  const float* br = (const float*)d_in[5];
  const float* att = (const float*)d_in[6];
  const float* cb = (const float*)d_in[7];
  const float* gamma = (const float*)d_in[8];
  const float* beta = (const float*)d_in[9];
  const float* linW = (const float*)d_in[10];
  const float* linb = (const float*)d_in[11];
  const float* ae = (const float*)d_in[12];
  const float* be = (const float*)d_in[13];
  const float* dec2W = (const float*)d_in[14];
  const float* dec2b = (const float*)d_in[15];

  int N = in_sizes[0] / DD;
  int E = in_sizes[1] / 2;
  size_t ND = (size_t)N * DD;
  int B = (N + 255) / 256;

  char* wsb = (char*)d_ws;
  size_t o = 0;
  auto alloc = [&](size_t bytes) {
    void* p = wsb + o;
    o += (bytes + 15) & ~(size_t)15;
    return p;
  };
  ushort* xb  = (ushort*)alloc(ND * 2);
  ushort* xlb = (ushort*)alloc(ND * 2);
  ushort* xrb = (ushort*)alloc(ND * 2);
  ushort* hfb = (ushort*)alloc(ND * 2);
  ushort* zbb = (ushort*)alloc(ND * 2);
  ushort* WlP = (ushort*)alloc(DD * DD * 2);
  ushort* WrP = (ushort*)alloc(DD * DD * 2);
  ushort* W1P = (ushort*)alloc(DD * DD * 2);
  ushort* W2P = (ushort*)alloc(DD * DD * 2);
  float* b1p   = (float*)alloc(DD * 4);
  float* b2pp  = (float*)alloc(DD * 4);
  // deg (padded) + bnsumC contiguous -> single memset
  int* deg       = (int*)alloc(((size_t)N << PADS) * 4 + 64);
  float* bnsumC  = (float*)alloc(NBCOPY * 2 * DD * 4);
  size_t clearBytes = (char*)(bnsumC + NBCOPY * 2 * DD) - (char*)deg;
  int* rowstart = (int*)alloc((size_t)(N + 1) * 4);
  int* cursor   = (int*)alloc(((size_t)N << PADS) * 4 + 64);
  int* bsum     = (int*)alloc((size_t)B * 4);
  int* boff     = (int*)alloc((size_t)B * 4);
  int* csr_src  = (int*)alloc((size_t)E * 4);

  float* z = (float*)d_out;
  float* v1 = z + ND;
  float* v2 = v1 + E;

  hipMemsetAsync(deg, 0, clearBytes, stream);

  int total4 = (int)(ND / 4);
  int convB = (total4 + 255) / 256;
  int packB = 128;
  int degB = (E + 255) / 256;
  k_prep<<<convB + packB + degB, 256, 0, stream>>>(x, xb, total4, Wl, Wr, WlP,
                                                   WrP, ei, deg, E, convB, packB);
  k_part<<<B, 256, 0, stream>>>(deg, rowstart, bsum, N);
  k_mid<<<1, 1024, 0, stream>>>(bsum, boff, rowstart + N, B);
  k_apply<<<B, 256, 0, stream>>>(rowstart, cursor, boff, N);
  int mmB = (N + 63) / 64;
  int fillB = (E + 255) / 256;
  k_lrfill<<<mmB + fillB, 256, 0, stream>>>(xb, WlP, WrP, bl, br, xlb, xrb, N,
                                            mmB, ei, cursor, csr_src, E);
  k_agg<<<(N + 3) / 4, 256, 0, stream>>>(xlb, xrb, rowstart, csr_src, att, cb,
                                         hfb, bnsumC, N);
  k_fold<<<129, 256, 0, stream>>>(bnsumC, gamma, beta, linW, linb, dec2W,
                                  dec2b, b1p, b2pp, W1P, W2P, N);
  k_mmz1<<<(N + 63) / 64, 256, 0, stream>>>(hfb, W1P, b1p, z, zbb, N);
  int v2B = (N + 63) / 64;
  int edgeB = 2048;
  k_v2edge<<<v2B + edgeB, 256, 0, stream>>>(hfb, W2P, b2pp, v2, N, v2B, zbb,
                                            ei, ae, be, v1, E, edgeB);
}